// Round 6
// baseline (1299.278 us; speedup 1.0000x reference)
//
#include <hip/hip_runtime.h>
#include <cstdint>

#define DEV __device__ __forceinline__

typedef __attribute__((ext_vector_type(8))) short short8;
typedef __attribute__((ext_vector_type(4))) float floatx4;
typedef unsigned short u16;
typedef unsigned int u32;

DEV u16 f2bf(float f) {
    unsigned u = __float_as_uint(f);
    return (u16)((u + 0x7fffu + ((u >> 16) & 1u)) >> 16);  // RNE
}
DEV void unpack2(u32 u, float& a, float& b) {
    a = __uint_as_float(u << 16);
    b = __uint_as_float(u & 0xffff0000u);
}
DEV u32 pack2f(float a, float b) { return (u32)f2bf(a) | ((u32)f2bf(b) << 16); }
DEV float sigm(float x) { return 1.0f / (1.0f + __expf(-x)); }

// Problem constants
#define NAG 8
#define DM 256
#define NL 4
#define AD 12
#define MROWS 32
#define NBLK 4096

// ws (bf16 units) offsets: weights in MFMA B-frag order [ks][n][quad][j]
#define OFF_E1   0
#define OFF_E2   8192
#define OFF_QKVO 73728        // 16 matrices of 65536: (l*4+m), m: 0=q 1=k 2=v 3=o
#define OFF_TW2  1122304
#define OFF_ADW  1126400
#define WS_TOTAL 1128448
#define WS_BYTES (WS_TOTAL * 2)

// dynamic LDS (bytes), total 51712 -> 3 blocks/CU
#define L_R1    0         // 33792: q[32][264]u16 @0 + k @16896 | trunk swizzled [256][64]u16 | head-x fp32 [32][264]
#define L_R2    33792     // 16896: state/nx/V [32][264]u16 ; bias tmp bf16 [4tok][4l][8h][64]
#define L_RED   50688     // 512: rms partials fp32 [32][4]
#define L_SPOS  51200     // 256
#define L_SVEL  51456     // 256
#define SMEM_BYTES 51712

// trunk swizzle: element (row, col) -> row*64 + ((col>>3 ^ (row&7))<<3) + (col&7)
#define TRK(row, col) ((row) * 64 + ((((col) >> 3) ^ ((row) & 7)) << 3) + ((col) & 7))

enum { I_STATE=0, I_POS, I_VEL, I_TEAM, I_ALIVE, I_DEAD, I_EW1, I_EB1, I_EW2, I_EB2,
       I_TEMB, I_SEMB, I_TW1, I_TB1, I_TW2, I_TB2, I_ADW, I_ADB, I_NORMW,
       I_WQ, I_BQ, I_WK, I_BK, I_WV, I_BV, I_WO, I_BO, I_HW, I_HB, N_IN };

struct Args { const void* in[N_IN]; float* out; };

// ---------------- weight pre-conversion: fp32 [K][N] -> bf16 frag order ----------------
__global__ __launch_bounds__(256) void prep_kernel(Args a, u16* ws)
{
    int e = blockIdx.x * 256 + threadIdx.x;
    int mat = blockIdx.y;
    int size, offs, N, Kreal;
    const float* src;
    if (mat == 0)      { size = 8192;  offs = OFF_E1;  N = 256; Kreal = 16;  src = (const float*)a.in[I_EW1]; }
    else if (mat == 1) { size = 65536; offs = OFF_E2;  N = 256; Kreal = 256; src = (const float*)a.in[I_EW2]; }
    else if (mat < 18) {
        int q = mat - 2, l = q >> 2, m = q & 3;
        int wi = (m == 0) ? I_WQ : (m == 1) ? I_WK : (m == 2) ? I_WV : I_WO;
        size = 65536; offs = OFF_QKVO + q * 65536; N = 256; Kreal = 256;
        src = (const float*)a.in[wi] + l * 65536;
    }
    else if (mat == 18) { size = 4096; offs = OFF_TW2; N = 64; Kreal = 64; src = (const float*)a.in[I_TW2]; }
    else                { size = 2048; offs = OFF_ADW; N = 32; Kreal = 64; src = (const float*)a.in[I_ADW]; }
    if (e >= size) return;
    int ksblk = N * 32;
    int ks = e / ksblk, rem = e % ksblk;
    int n = rem >> 5, quad = (rem >> 3) & 3, j = rem & 7;
    int k = ks * 32 + quad * 8 + j;
    float v = 0.0f;
    if (k < Kreal) {
        if (mat == 19) v = src[((n >> 3) * 64 + k) * 8 + (n & 7)];   // adapt_W[l][k][h], n=l*8+h
        else           v = src[k * N + n];
    }
    ws[offs + e] = f2bf(v);
}

// ---------------- MFMA fragment loaders ----------------
DEV short8 ld_u4(const u16* p) {
    union { uint4 u; short8 s; } c;
    c.u = *(const uint4*)p;
    return c.s;
}
DEV short8 ld_afrag(const u16* A, int stride, int row0, int kofs, int l15, int quad) {
    return ld_u4(A + (row0 + l15) * stride + kofs + quad * 8);
}
DEV short8 ld_bws(const u16* w, int ksblk, int ks, int col, int l15, int quad) {
    return ld_u4(w + ks * ksblk + (col + l15) * 32 + quad * 8);
}
DEV short8 ld_bf32(const float* W, int N, int Kreal, int ks, int col, int l15, int quad) {
    short8 r;
    #pragma unroll
    for (int j = 0; j < 8; j++) {
        int k = ks * 32 + quad * 8 + j;
        float v = (k < Kreal) ? W[k * N + col + l15] : 0.0f;
        r[j] = (short)f2bf(v);
    }
    return r;
}

// M=32 GEMM: A [32][264] bf16 LDS, wave covers cols [colw, colw+64)
template<bool UW>
DEV void gemm32(const u16* A, const u16* wsW, const float* Wf,
                int Kb, int Kreal, int colw, int l15, int quad, floatx4 acc[2][4]) {
    for (int ks = 0; ks < Kb; ks++) {
        short8 af0 = ld_afrag(A, 264, 0,  ks * 32, l15, quad);
        short8 af1 = ld_afrag(A, 264, 16, ks * 32, l15, quad);
        short8 bf[4];
        #pragma unroll
        for (int nj = 0; nj < 4; nj++)
            bf[nj] = UW ? ld_bws(wsW, 8192, ks, colw + nj * 16, l15, quad)
                        : ld_bf32(Wf, 256, Kreal, ks, colw + nj * 16, l15, quad);
        #pragma unroll
        for (int nj = 0; nj < 4; nj++) {
            acc[0][nj] = __builtin_amdgcn_mfma_f32_16x16x32_bf16(af0, bf[nj], acc[0][nj], 0, 0, 0);
            acc[1][nj] = __builtin_amdgcn_mfma_f32_16x16x32_bf16(af1, bf[nj], acc[1][nj], 0, 0, 0);
        }
    }
}

template<bool UW>
__global__ __launch_bounds__(256, 3) void yemong_mfma(Args a, const u16* ws)
{
    extern __shared__ char smem[];
    u16* sR1   = (u16*)(smem + L_R1);     // q / trunk / head-x
    u16* skb   = (u16*)(smem + L_R1 + 16896);  // k
    u16* sR2   = (u16*)(smem + L_R2);     // state / nx / V / bias-tmp
    float* sred = (float*)(smem + L_RED);
    float* spos = (float*)(smem + L_SPOS);
    float* svel = (float*)(smem + L_SVEL);

    const int t = threadIdx.x, bid = blockIdx.x;
    const int lane = t & 63, w = t >> 6;
    const int l15 = lane & 15, quad = lane >> 4;
    const int colw = w * 64;
    const int p = w >> 1, h0 = (w & 1) * 4;   // attention pair / head base

    float xr[2][4][4];        // residual x (C-layout): row=mi*16+quad*4+r, col=colw+nj*16+l15
    u32 br[NL][4][2];         // attn bias, packed bf16 x4 per (layer, unit)
    u32 amask;                // alive bits of this lane's attention token

    // alive-layout probe (byte bools vs int32 bools), uniform
    unsigned mp = 0;
    const unsigned* au = (const unsigned*)a.in[I_ALIVE];
    #pragma unroll
    for (int i = 0; i < 16; i++) mp |= au[i];
    const bool abyte = (mp > 1u);
    auto aliveAt = [&](int r) -> int {
        int gi = bid * MROWS + r;
        return abyte ? (int)((const unsigned char*)a.in[I_ALIVE])[gi]
                     : ((const int*)a.in[I_ALIVE])[gi];
    };

    // -------- P0: metadata + masked state staging --------
    if (t < 64) {
        int n = t >> 1, d = t & 1;
        spos[n * 2 + d] = ((const float*)a.in[I_POS])[(bid * MROWS + n) * 2 + d] * 1024.0f;
        svel[n * 2 + d] = ((const float*)a.in[I_VEL])[(bid * MROWS + n) * 2 + d];
    }
    {
        int tk = 2 * p + (quad >> 1);
        amask = 0;
        #pragma unroll
        for (int j = 0; j < 8; j++) amask |= (aliveAt(tk * 8 + j) ? 1u : 0u) << j;
    }
    {
        const float* gs = (const float*)a.in[I_STATE];
        const float* gd = (const float*)a.in[I_DEAD];
        #pragma unroll
        for (int it = 0; it < 4; it++) {
            int idx = t + 256 * it;              // 32 rows x 32 k
            int r = idx >> 5, kk = idx & 31;
            float v = 0.0f;
            if (kk < 16) v = aliveAt(r) ? gs[(bid * MROWS + r) * 16 + kk] : gd[kk];
            sR2[r * 264 + kk] = f2bf(v);
        }
    }
    __syncthreads();

    // -------- P1: enc1 (16->256) + silu, in place over R2 --------
    {
        floatx4 acc[2][4] = {};
        gemm32<UW>(sR2, ws + OFF_E1, (const float*)a.in[I_EW1], 1, 16, colw, l15, quad, acc);
        __syncthreads();
        const float* b1 = (const float*)a.in[I_EB1];
        #pragma unroll
        for (int nj = 0; nj < 4; nj++) {
            int c = colw + nj * 16 + l15;
            float bb = b1[c];
            #pragma unroll
            for (int mi = 0; mi < 2; mi++)
                #pragma unroll
                for (int r = 0; r < 4; r++) {
                    float v = acc[mi][nj][r] + bb;
                    sR2[(mi * 16 + quad * 4 + r) * 264 + c] = f2bf(v * sigm(v));
                }
        }
    }
    __syncthreads();

    // -------- P2: enc2 (256->256) + b2 + embeddings -> xr --------
    {
        floatx4 acc[2][4] = {};
        gemm32<UW>(sR2, ws + OFF_E2, (const float*)a.in[I_EW2], 8, 256, colw, l15, quad, acc);
        const float* b2 = (const float*)a.in[I_EB2];
        const float* te = (const float*)a.in[I_TEMB];
        const float* se = (const float*)a.in[I_SEMB];
        const int* gteam = (const int*)a.in[I_TEAM];
        int team8[8];
        #pragma unroll
        for (int mi = 0; mi < 2; mi++)
            #pragma unroll
            for (int r = 0; r < 4; r++)
                team8[mi * 4 + r] = gteam[bid * MROWS + mi * 16 + quad * 4 + r];
        #pragma unroll
        for (int nj = 0; nj < 4; nj++) {
            int c = colw + nj * 16 + l15;
            float bb = b2[c];
            #pragma unroll
            for (int mi = 0; mi < 2; mi++)
                #pragma unroll
                for (int r = 0; r < 4; r++) {
                    int row = mi * 16 + quad * 4 + r;
                    xr[mi][nj][r] = acc[mi][nj][r] + bb + te[team8[mi * 4 + r] * 256 + c] + se[(row & 7) * 256 + c];
                }
        }
    }

    // -------- P3a: pair features + trunk1 (6->64) + silu -> swizzled trunk [256][64] --------
    {
        int tokp = t >> 6;
        int pi = tokp * 8 + ((t >> 3) & 7), pj = tokp * 8 + (t & 7);
        float rx = spos[pi * 2 + 0] - spos[pj * 2 + 0];
        float ry = spos[pi * 2 + 1] - spos[pj * 2 + 1];
        rx -= rintf(rx * (1.0f / 1024.0f)) * 1024.0f;
        ry -= rintf(ry * (1.0f / 1024.0f)) * 1024.0f;
        float vx = svel[pi * 2 + 0] - svel[pj * 2 + 0];
        float vy = svel[pi * 2 + 1] - svel[pj * 2 + 1];
        float dn = sqrtf(rx * rx + ry * ry + 1e-8f) * (1.0f / 1024.0f);
        float f[6] = {rx * (1.0f / 1024.0f), ry * (1.0f / 1024.0f), vx, vy, dn, 1.0f / (1.0f + dn)};
        const float* W1 = (const float*)a.in[I_TW1];
        const float* B1 = (const float*)a.in[I_TB1];
        #pragma unroll
        for (int g = 0; g < 8; g++) {
            float v[8];
            #pragma unroll
            for (int e = 0; e < 8; e++) v[e] = B1[g * 8 + e];
            #pragma unroll
            for (int kk = 0; kk < 6; kk++)
                #pragma unroll
                for (int e = 0; e < 8; e++) v[e] = fmaf(f[kk], W1[kk * 64 + g * 8 + e], v[e]);
            #pragma unroll
            for (int e = 0; e < 8; e++) v[e] = v[e] * sigm(v[e]);
            uint4 pk;
            pk.x = pack2f(v[0], v[1]); pk.y = pack2f(v[2], v[3]);
            pk.z = pack2f(v[4], v[5]); pk.w = pack2f(v[6], v[7]);
            *(uint4*)&sR1[t * 64 + ((g ^ (t & 7)) << 3)] = pk;
        }
    }
    __syncthreads();

    // -------- P3b: trunk2 (64->64) MFMA, in place (wave-local rows, swizzled) --------
    {
        short8 taf[4][2];
        #pragma unroll
        for (int mi = 0; mi < 4; mi++)
            #pragma unroll
            for (int ks = 0; ks < 2; ks++) {
                int R = colw + mi * 16 + l15;
                taf[mi][ks] = ld_u4(&sR1[R * 64 + (((ks * 4 + quad) ^ (R & 7)) << 3)]);
            }
        floatx4 tacc[4][4] = {};
        #pragma unroll
        for (int ks = 0; ks < 2; ks++) {
            short8 bf[4];
            #pragma unroll
            for (int nj = 0; nj < 4; nj++)
                bf[nj] = UW ? ld_bws(ws + OFF_TW2, 2048, ks, nj * 16, l15, quad)
                            : ld_bf32((const float*)a.in[I_TW2], 64, 64, ks, nj * 16, l15, quad);
            #pragma unroll
            for (int mi = 0; mi < 4; mi++)
                #pragma unroll
                for (int nj = 0; nj < 4; nj++)
                    tacc[mi][nj] = __builtin_amdgcn_mfma_f32_16x16x32_bf16(taf[mi][ks], bf[nj], tacc[mi][nj], 0, 0, 0);
        }
        const float* B2 = (const float*)a.in[I_TB2];
        #pragma unroll
        for (int nj = 0; nj < 4; nj++) {
            int c = nj * 16 + l15;
            float bb = B2[c];
            #pragma unroll
            for (int mi = 0; mi < 4; mi++)
                #pragma unroll
                for (int r = 0; r < 4; r++) {
                    int row = colw + mi * 16 + quad * 4 + r;
                    sR1[TRK(row, c)] = f2bf(tacc[mi][nj][r] + bb);
                }
        }
    }
    __syncthreads();

    // -------- P3c: adapt (64->32) -> bias tmp (R2) -> bias regs --------
    {
        floatx4 tacc[4][2] = {};
        #pragma unroll
        for (int ks = 0; ks < 2; ks++) {
            short8 bf[2];
            #pragma unroll
            for (int nj = 0; nj < 2; nj++) {
                if (UW) bf[nj] = ld_bws(ws + OFF_ADW, 1024, ks, nj * 16, l15, quad);
                else {
                    const float* adw = (const float*)a.in[I_ADW];
                    int n = nj * 16 + l15;
                    #pragma unroll
                    for (int j = 0; j < 8; j++) {
                        int k = ks * 32 + quad * 8 + j;
                        bf[nj][j] = (short)f2bf(k < 64 ? adw[((n >> 3) * 64 + k) * 8 + (n & 7)] : 0.0f);
                    }
                }
            }
            #pragma unroll
            for (int mi = 0; mi < 4; mi++) {
                int R = colw + mi * 16 + l15;
                short8 af = ld_u4(&sR1[R * 64 + (((ks * 4 + quad) ^ (R & 7)) << 3)]);
                #pragma unroll
                for (int nj = 0; nj < 2; nj++)
                    tacc[mi][nj] = __builtin_amdgcn_mfma_f32_16x16x32_bf16(af, bf[nj], tacc[mi][nj], 0, 0, 0);
            }
        }
        const float* adb = (const float*)a.in[I_ADB];
        #pragma unroll
        for (int nj = 0; nj < 2; nj++) {
            int n = nj * 16 + l15;
            float bb = adb[n];
            #pragma unroll
            for (int mi = 0; mi < 4; mi++)
                #pragma unroll
                for (int r = 0; r < 4; r++) {
                    int pl = mi * 16 + quad * 4 + r;   // pair idx within token (wave = token)
                    sR2[((w * 4 + (n >> 3)) * 8 + (n & 7)) * 64 + pl] = f2bf(tacc[mi][nj][r] + bb);
                }
        }
        __syncthreads();
        // extract per-lane bias regs: for (layer, unit) 4 consecutive j values
        int tk = 2 * p + (quad >> 1);
        #pragma unroll
        for (int l = 0; l < NL; l++)
            #pragma unroll
            for (int u = 0; u < 4; u++) {
                int base = ((tk * 4 + l) * 8 + (h0 + u)) * 64 + (l15 & 7) * 8 + (quad & 1) * 4;
                const u32* bp = (const u32*)&sR2[base];
                br[l][u][0] = bp[0];
                br[l][u][1] = bp[1];
            }
    }
    __syncthreads();   // bias reads done; R2 free for nx

    // -------- P4: layers --------
    const float* normw = (const float*)a.in[I_NORMW];
    const bool qvalid = ((quad >> 1) == (l15 >> 3));
    for (int l = 0; l < NL; l++) {
        // (a) rms
        float invr[8];
        {
            float ssv[8];
            #pragma unroll
            for (int mi = 0; mi < 2; mi++)
                #pragma unroll
                for (int r = 0; r < 4; r++) {
                    float s = 0.0f;
                    #pragma unroll
                    for (int nj = 0; nj < 4; nj++) { float v = xr[mi][nj][r]; s = fmaf(v, v, s); }
                    ssv[mi * 4 + r] = s;
                }
            #pragma unroll
            for (int m = 1; m < 16; m <<= 1)
                #pragma unroll
                for (int k2 = 0; k2 < 8; k2++) ssv[k2] += __shfl_xor(ssv[k2], m);
            if (l15 == 0) {
                #pragma unroll
                for (int mi = 0; mi < 2; mi++)
                    #pragma unroll
                    for (int r = 0; r < 4; r++)
                        sred[(mi * 16 + quad * 4 + r) * 4 + w] = ssv[mi * 4 + r];
            }
            __syncthreads();
            #pragma unroll
            for (int mi = 0; mi < 2; mi++)
                #pragma unroll
                for (int r = 0; r < 4; r++) {
                    int row = mi * 16 + quad * 4 + r;
                    float s = sred[row * 4 + 0] + sred[row * 4 + 1] + sred[row * 4 + 2] + sred[row * 4 + 3];
                    invr[mi * 4 + r] = rsqrtf(s * (1.0f / 256.0f) + 1e-6f);
                }
        }
        // (b) nx -> R2
        {
            #pragma unroll
            for (int nj = 0; nj < 4; nj++) {
                int c = colw + nj * 16 + l15;
                float nwv = normw[l * 256 + c];
                #pragma unroll
                for (int mi = 0; mi < 2; mi++)
                    #pragma unroll
                    for (int r = 0; r < 4; r++)
                        sR2[(mi * 16 + quad * 4 + r) * 264 + c] = f2bf(xr[mi][nj][r] * invr[mi * 4 + r] * nwv);
            }
        }
        __syncthreads();

        // (c) Q, K projections (stores overlap other waves' nx reads safely: R1 vs R2)
        {
            floatx4 acc[2][4] = {};
            gemm32<UW>(sR2, ws + OFF_QKVO + (l * 4 + 0) * 65536, (const float*)a.in[I_WQ] + l * 65536, 8, 256, colw, l15, quad, acc);
            const float* bq = (const float*)a.in[I_BQ] + l * 256;
            #pragma unroll
            for (int nj = 0; nj < 4; nj++) {
                int c = colw + nj * 16 + l15;
                float bb = bq[c];
                #pragma unroll
                for (int mi = 0; mi < 2; mi++)
                    #pragma unroll
                    for (int r = 0; r < 4; r++)
                        sR1[(mi * 16 + quad * 4 + r) * 264 + c] = f2bf((acc[mi][nj][r] + bb) * 0.17677669529663689f);
            }
        }
        {
            floatx4 acc[2][4] = {};
            gemm32<UW>(sR2, ws + OFF_QKVO + (l * 4 + 1) * 65536, (const float*)a.in[I_WK] + l * 65536, 8, 256, colw, l15, quad, acc);
            const float* bk = (const float*)a.in[I_BK] + l * 256;
            #pragma unroll
            for (int nj = 0; nj < 4; nj++) {
                int c = colw + nj * 16 + l15;
                float bb = bk[c];
                #pragma unroll
                for (int mi = 0; mi < 2; mi++)
                    #pragma unroll
                    for (int r = 0; r < 4; r++)
                        skb[(mi * 16 + quad * 4 + r) * 264 + c] = f2bf(acc[mi][nj][r] + bb);
            }
        }
        // V projection; store must wait for all waves' nx reads
        {
            floatx4 acc[2][4] = {};
            gemm32<UW>(sR2, ws + OFF_QKVO + (l * 4 + 2) * 65536, (const float*)a.in[I_WV] + l * 65536, 8, 256, colw, l15, quad, acc);
            __syncthreads();
            const float* bv = (const float*)a.in[I_BV] + l * 256;
            #pragma unroll
            for (int nj = 0; nj < 4; nj++) {
                int c = colw + nj * 16 + l15;
                float bb = bv[c];
                #pragma unroll
                for (int mi = 0; mi < 2; mi++)
                    #pragma unroll
                    for (int r = 0; r < 4; r++)
                        sR2[(mi * 16 + quad * 4 + r) * 264 + c] = f2bf(acc[mi][nj][r] + bb);
            }
        }
        __syncthreads();   // q, k, v visible

        // (d/e) MFMA attention: 4 units (pair p, head h0+u); O overwrites q (disjoint cols)
        #pragma unroll
        for (int u = 0; u < 4; u++) {
            int h = h0 + u;
            short8 kf = ld_u4(&skb[(p * 16 + l15) * 264 + h * 32 + quad * 8]);
            short8 qf = ld_u4(&sR1[(p * 16 + l15) * 264 + h * 32 + quad * 8]);
            floatx4 zero = {};
            floatx4 st = __builtin_amdgcn_mfma_f32_16x16x32_bf16(kf, qf, zero, 0, 0, 0);
            float bb[4];
            unpack2(br[l][u][0], bb[0], bb[1]);
            unpack2(br[l][u][1], bb[2], bb[3]);
            float s[4];
            #pragma unroll
            for (int r = 0; r < 4; r++) {
                int jl = (quad & 1) * 4 + r;
                bool alv = (amask >> jl) & 1;
                s[r] = qvalid ? (alv ? st[r] + bb[r] : -1.0e9f) : -2.0e9f;
            }
            float mx = fmaxf(fmaxf(s[0], s[1]), fmaxf(s[2], s[3]));
            mx = fmaxf(mx, __shfl_xor(mx, 16));
            mx = fmaxf(mx, __shfl_xor(mx, 32));
            float e[4], sm = 0.0f;
            #pragma unroll
            for (int r = 0; r < 4; r++) { e[r] = __expf(s[r] - mx); sm += e[r]; }
            sm += __shfl_xor(sm, 16);
            sm += __shfl_xor(sm, 32);
            float inv = 1.0f / sm;
            u32 u01 = pack2f(e[0] * inv, e[1] * inv);
            u32 u23 = pack2f(e[2] * inv, e[3] * inv);
            // redistribute P^T lanes into PV A-frag (k = quad*8 + jj)
            int srcA = (quad * 32 + l15) & 63;
            u32 a0 = (u32)__shfl((int)u01, srcA);
            u32 a1 = (u32)__shfl((int)u23, srcA);
            u32 a2 = (u32)__shfl((int)u01, (srcA + 16) & 63);
            u32 a3 = (u32)__shfl((int)u23, (srcA + 16) & 63);
            if (quad >= 2) { a0 = 0; a1 = 0; a2 = 0; a3 = 0; }
            union { u32 uu[4]; short8 ss; } cv;
            cv.uu[0] = a0; cv.uu[1] = a1; cv.uu[2] = a2; cv.uu[3] = a3;
            short8 paf = cv.ss;
            #pragma unroll
            for (int nt = 0; nt < 2; nt++) {
                short8 vf;
                #pragma unroll
                for (int jj = 0; jj < 8; jj++) {
                    int kr = (quad * 8 + jj) & 15;
                    vf[jj] = (short)sR2[(p * 16 + kr) * 264 + h * 32 + nt * 16 + l15];
                }
                floatx4 z2 = {};
                floatx4 o = __builtin_amdgcn_mfma_f32_16x16x32_bf16(paf, vf, z2, 0, 0, 0);
                #pragma unroll
                for (int r = 0; r < 4; r++)
                    sR1[(p * 16 + quad * 4 + r) * 264 + h * 32 + nt * 16 + l15] = f2bf(o[r]);
            }
        }
        __syncthreads();   // O visible

        // (f) x += O @ Wo + bo
        {
            floatx4 acc[2][4] = {};
            gemm32<UW>(sR1, ws + OFF_QKVO + (l * 4 + 3) * 65536, (const float*)a.in[I_WO] + l * 65536,
                       8, 256, colw, l15, quad, acc);
            const float* bo = (const float*)a.in[I_BO] + l * 256;
            #pragma unroll
            for (int nj = 0; nj < 4; nj++) {
                float bb = bo[colw + nj * 16 + l15];
                #pragma unroll
                for (int mi = 0; mi < 2; mi++)
                    #pragma unroll
                    for (int r = 0; r < 4; r++)
                        xr[mi][nj][r] += acc[mi][nj][r] + bb;
            }
        }
        __syncthreads();   // O reads done before next layer / head staging
    }

    // -------- P5: stage x -> R1 fp32, then head (256 -> 12) --------
    {
        float* xf = (float*)sR1;
        #pragma unroll
        for (int nj = 0; nj < 4; nj++) {
            int c = colw + nj * 16 + l15;
            #pragma unroll
            for (int mi = 0; mi < 2; mi++)
                #pragma unroll
                for (int r = 0; r < 4; r++)
                    xf[(mi * 16 + quad * 4 + r) * 264 + c] = xr[mi][nj][r];
        }
        __syncthreads();
        int row = t >> 3, pp = t & 7;
        const float* HW = (const float*)a.in[I_HW];
        float ah[12];
        #pragma unroll
        for (int c = 0; c < 12; c++) ah[c] = 0.0f;
        for (int kk = pp * 32; kk < pp * 32 + 32; kk++) {
            float xv = xf[row * 264 + kk];
            #pragma unroll
            for (int c = 0; c < 12; c++) ah[c] = fmaf(xv, HW[kk * 12 + c], ah[c]);
        }
        #pragma unroll
        for (int c = 0; c < 12; c++) {
            ah[c] += __shfl_xor(ah[c], 1);
            ah[c] += __shfl_xor(ah[c], 2);
            ah[c] += __shfl_xor(ah[c], 4);
        }
        if (pp == 0) {
            const float* hb = (const float*)a.in[I_HB];
            #pragma unroll
            for (int c = 0; c < 12; c++)
                a.out[(bid * MROWS + row) * AD + c] = ah[c] + hb[c];
        }
    }
}

extern "C" void kernel_launch(void* const* d_in, const int* in_sizes, int n_in,
                              void* d_out, int out_size, void* d_ws, size_t ws_size,
                              hipStream_t stream) {
    (void)in_sizes; (void)n_in; (void)out_size;
    Args a;
    for (int i = 0; i < N_IN; i++) a.in[i] = d_in[i];
    a.out = (float*)d_out;
    u16* ws16 = (u16*)d_ws;
    const bool use_ws = (ws_size >= (size_t)WS_BYTES) && (d_ws != nullptr);
    if (use_ws) {
        hipLaunchKernelGGL(prep_kernel, dim3(256, 20), dim3(256), 0, stream, a, ws16);
        hipFuncSetAttribute((const void*)yemong_mfma<true>, hipFuncAttributeMaxDynamicSharedMemorySize, SMEM_BYTES);
        hipLaunchKernelGGL((yemong_mfma<true>), dim3(NBLK), dim3(256), SMEM_BYTES, stream, a, ws16);
    } else {
        hipFuncSetAttribute((const void*)yemong_mfma<false>, hipFuncAttributeMaxDynamicSharedMemorySize, SMEM_BYTES);
        hipLaunchKernelGGL((yemong_mfma<false>), dim3(NBLK), dim3(256), SMEM_BYTES, stream, a, ws16);
    }
}

// Round 7
// 1216.991 us; speedup vs baseline: 1.0676x; 1.0676x over previous
//
#include <hip/hip_runtime.h>
#include <cstdint>

#define DEV __device__ __forceinline__

typedef __attribute__((ext_vector_type(8))) short short8;
typedef __attribute__((ext_vector_type(4))) float floatx4;
typedef unsigned short u16;
typedef unsigned int u32;

DEV u16 f2bf(float f) {
    unsigned u = __float_as_uint(f);
    return (u16)((u + 0x7fffu + ((u >> 16) & 1u)) >> 16);  // RNE
}
DEV void unpack2(u32 u, float& a, float& b) {
    a = __uint_as_float(u << 16);
    b = __uint_as_float(u & 0xffff0000u);
}
DEV u32 pack2f(float a, float b) { return (u32)f2bf(a) | ((u32)f2bf(b) << 16); }
DEV float sigm(float x) { return 1.0f / (1.0f + __expf(-x)); }

// Problem constants
#define NAG 8
#define DM 256
#define NL 4
#define AD 12
#define MROWS 32
#define NBLK 4096

// ws (bf16 units) offsets: weights in MFMA B-frag order [ks][n][quad][j]
#define OFF_E1   0
#define OFF_E2   8192
#define OFF_QKVO 73728        // 16 matrices of 65536: (l*4+m), m: 0=q 1=k 2=v 3=o
#define OFF_TW2  1122304
#define OFF_ADW  1126400
#define WS_TOTAL 1128448
#define WS_BYTES (WS_TOTAL * 2)

// dynamic LDS (bytes), total 51712 -> 3 blocks/CU
#define L_R1    0         // 33792: q[32][264]u16 @0 + k @16896 | trunk swizzled [256][64]u16 | head-x fp32 [32][264]
#define L_R2    33792     // 16896: state/nx/V [32][264]u16 ; bias tmp bf16 [4tok][4l][8h][64]
#define L_RED   50688     // 512: rms partials fp32 [32][4]
#define L_SPOS  51200     // 256
#define L_SVEL  51456     // 256
#define SMEM_BYTES 51712

// trunk swizzle: element (row, col) -> row*64 + ((col>>3 ^ (row&7))<<3) + (col&7)
#define TRK(row, col) ((row) * 64 + ((((col) >> 3) ^ ((row) & 7)) << 3) + ((col) & 7))

enum { I_STATE=0, I_POS, I_VEL, I_TEAM, I_ALIVE, I_DEAD, I_EW1, I_EB1, I_EW2, I_EB2,
       I_TEMB, I_SEMB, I_TW1, I_TB1, I_TW2, I_TB2, I_ADW, I_ADB, I_NORMW,
       I_WQ, I_BQ, I_WK, I_BK, I_WV, I_BV, I_WO, I_BO, I_HW, I_HB, N_IN };

struct Args { const void* in[N_IN]; float* out; };

// ---------------- weight pre-conversion: fp32 [K][N] -> bf16 frag order ----------------
__global__ __launch_bounds__(256) void prep_kernel(Args a, u16* ws)
{
    int e = blockIdx.x * 256 + threadIdx.x;
    int mat = blockIdx.y;
    int size, offs, N, Kreal;
    const float* src;
    if (mat == 0)      { size = 8192;  offs = OFF_E1;  N = 256; Kreal = 16;  src = (const float*)a.in[I_EW1]; }
    else if (mat == 1) { size = 65536; offs = OFF_E2;  N = 256; Kreal = 256; src = (const float*)a.in[I_EW2]; }
    else if (mat < 18) {
        int q = mat - 2, l = q >> 2, m = q & 3;
        int wi = (m == 0) ? I_WQ : (m == 1) ? I_WK : (m == 2) ? I_WV : I_WO;
        size = 65536; offs = OFF_QKVO + q * 65536; N = 256; Kreal = 256;
        src = (const float*)a.in[wi] + l * 65536;
    }
    else if (mat == 18) { size = 4096; offs = OFF_TW2; N = 64; Kreal = 64; src = (const float*)a.in[I_TW2]; }
    else                { size = 2048; offs = OFF_ADW; N = 32; Kreal = 64; src = (const float*)a.in[I_ADW]; }
    if (e >= size) return;
    int ksblk = N * 32;
    int ks = e / ksblk, rem = e % ksblk;
    int n = rem >> 5, quad = (rem >> 3) & 3, j = rem & 7;
    int k = ks * 32 + quad * 8 + j;
    float v = 0.0f;
    if (k < Kreal) {
        if (mat == 19) v = src[((n >> 3) * 64 + k) * 8 + (n & 7)];   // adapt_W[l][k][h], n=l*8+h
        else           v = src[k * N + n];
    }
    ws[offs + e] = f2bf(v);
}

// ---------------- MFMA fragment loaders ----------------
DEV short8 ld_u4(const u16* p) {
    union { uint4 u; short8 s; } c;
    c.u = *(const uint4*)p;
    return c.s;
}
DEV short8 ld_afrag(const u16* A, int stride, int row0, int kofs, int l15, int quad) {
    return ld_u4(A + (row0 + l15) * stride + kofs + quad * 8);
}
DEV short8 ld_bws(const u16* w, int ksblk, int ks, int col, int l15, int quad) {
    return ld_u4(w + ks * ksblk + (col + l15) * 32 + quad * 8);
}
DEV short8 ld_bf32(const float* W, int N, int Kreal, int ks, int col, int l15, int quad) {
    short8 r;
    #pragma unroll
    for (int j = 0; j < 8; j++) {
        int k = ks * 32 + quad * 8 + j;
        float v = (k < Kreal) ? W[k * N + col + l15] : 0.0f;
        r[j] = (short)f2bf(v);
    }
    return r;
}

// M=32 GEMM: A [32][264] bf16 LDS, wave covers cols [colw, colw+64)
template<bool UW>
DEV void gemm32(const u16* A, const u16* wsW, const float* Wf,
                int Kb, int Kreal, int colw, int l15, int quad, floatx4 acc[2][4]) {
    for (int ks = 0; ks < Kb; ks++) {
        short8 af0 = ld_afrag(A, 264, 0,  ks * 32, l15, quad);
        short8 af1 = ld_afrag(A, 264, 16, ks * 32, l15, quad);
        short8 bf[4];
        #pragma unroll
        for (int nj = 0; nj < 4; nj++)
            bf[nj] = UW ? ld_bws(wsW, 8192, ks, colw + nj * 16, l15, quad)
                        : ld_bf32(Wf, 256, Kreal, ks, colw + nj * 16, l15, quad);
        #pragma unroll
        for (int nj = 0; nj < 4; nj++) {
            acc[0][nj] = __builtin_amdgcn_mfma_f32_16x16x32_bf16(af0, bf[nj], acc[0][nj], 0, 0, 0);
            acc[1][nj] = __builtin_amdgcn_mfma_f32_16x16x32_bf16(af1, bf[nj], acc[1][nj], 0, 0, 0);
        }
    }
}

template<bool UW>
__global__ __launch_bounds__(256, 3) void yemong_mfma(Args a, const u16* ws)
{
    extern __shared__ char smem[];
    u16* sR1   = (u16*)(smem + L_R1);     // q / trunk / head-x
    u16* skb   = (u16*)(smem + L_R1 + 16896);  // k
    u16* sR2   = (u16*)(smem + L_R2);     // state / nx / V / bias-tmp
    float* sred = (float*)(smem + L_RED);
    float* spos = (float*)(smem + L_SPOS);
    float* svel = (float*)(smem + L_SVEL);

    const int t = threadIdx.x, bid = blockIdx.x;
    const int lane = t & 63, w = t >> 6;
    const int l15 = lane & 15, quad = lane >> 4;
    const int colw = w * 64;
    const int p = w >> 1, h0 = (w & 1) * 4;   // attention pair / head base

    float xr[2][4][4];        // residual x (C-layout): row=mi*16+quad*4+r, col=colw+nj*16+l15
    u32 br[NL][4][2];         // attn bias, packed bf16 x4 per (layer, unit)
    u32 amask;                // alive bits of this lane's attention token

    // alive-layout probe (byte bools vs int32 bools), uniform
    unsigned mp = 0;
    const unsigned* au = (const unsigned*)a.in[I_ALIVE];
    #pragma unroll
    for (int i = 0; i < 16; i++) mp |= au[i];
    const bool abyte = (mp > 1u);
    auto aliveAt = [&](int r) -> int {
        int gi = bid * MROWS + r;
        return abyte ? (int)((const unsigned char*)a.in[I_ALIVE])[gi]
                     : ((const int*)a.in[I_ALIVE])[gi];
    };

    // -------- P0: metadata + masked state staging --------
    if (t < 64) {
        int n = t >> 1, d = t & 1;
        spos[n * 2 + d] = ((const float*)a.in[I_POS])[(bid * MROWS + n) * 2 + d] * 1024.0f;
        svel[n * 2 + d] = ((const float*)a.in[I_VEL])[(bid * MROWS + n) * 2 + d];
    }
    {
        int tk = 2 * p + (quad >> 1);
        amask = 0;
        #pragma unroll
        for (int j = 0; j < 8; j++) amask |= (aliveAt(tk * 8 + j) ? 1u : 0u) << j;
    }
    {
        const float* gs = (const float*)a.in[I_STATE];
        const float* gd = (const float*)a.in[I_DEAD];
        #pragma unroll
        for (int it = 0; it < 4; it++) {
            int idx = t + 256 * it;              // 32 rows x 32 k
            int r = idx >> 5, kk = idx & 31;
            float v = 0.0f;
            if (kk < 16) v = aliveAt(r) ? gs[(bid * MROWS + r) * 16 + kk] : gd[kk];
            sR2[r * 264 + kk] = f2bf(v);
        }
    }
    __syncthreads();

    // -------- P1: enc1 (16->256) + silu, in place over R2 --------
    {
        floatx4 acc[2][4] = {};
        gemm32<UW>(sR2, ws + OFF_E1, (const float*)a.in[I_EW1], 1, 16, colw, l15, quad, acc);
        __syncthreads();
        const float* b1 = (const float*)a.in[I_EB1];
        #pragma unroll
        for (int nj = 0; nj < 4; nj++) {
            int c = colw + nj * 16 + l15;
            float bb = b1[c];
            #pragma unroll
            for (int mi = 0; mi < 2; mi++)
                #pragma unroll
                for (int r = 0; r < 4; r++) {
                    float v = acc[mi][nj][r] + bb;
                    sR2[(mi * 16 + quad * 4 + r) * 264 + c] = f2bf(v * sigm(v));
                }
        }
    }
    __syncthreads();

    // -------- P2: enc2 (256->256) + b2 + embeddings -> xr --------
    {
        floatx4 acc[2][4] = {};
        gemm32<UW>(sR2, ws + OFF_E2, (const float*)a.in[I_EW2], 8, 256, colw, l15, quad, acc);
        const float* b2 = (const float*)a.in[I_EB2];
        const float* te = (const float*)a.in[I_TEMB];
        const float* se = (const float*)a.in[I_SEMB];
        const int* gteam = (const int*)a.in[I_TEAM];
        int team8[8];
        #pragma unroll
        for (int mi = 0; mi < 2; mi++)
            #pragma unroll
            for (int r = 0; r < 4; r++)
                team8[mi * 4 + r] = gteam[bid * MROWS + mi * 16 + quad * 4 + r];
        #pragma unroll
        for (int nj = 0; nj < 4; nj++) {
            int c = colw + nj * 16 + l15;
            float bb = b2[c];
            #pragma unroll
            for (int mi = 0; mi < 2; mi++)
                #pragma unroll
                for (int r = 0; r < 4; r++) {
                    int row = mi * 16 + quad * 4 + r;
                    xr[mi][nj][r] = acc[mi][nj][r] + bb + te[team8[mi * 4 + r] * 256 + c] + se[(row & 7) * 256 + c];
                }
        }
    }

    // -------- P3a: pair features + trunk1 (6->64) + silu -> swizzled trunk [256][64] --------
    {
        int tokp = t >> 6;
        int pi = tokp * 8 + ((t >> 3) & 7), pj = tokp * 8 + (t & 7);
        float rx = spos[pi * 2 + 0] - spos[pj * 2 + 0];
        float ry = spos[pi * 2 + 1] - spos[pj * 2 + 1];
        rx -= rintf(rx * (1.0f / 1024.0f)) * 1024.0f;
        ry -= rintf(ry * (1.0f / 1024.0f)) * 1024.0f;
        float vx = svel[pi * 2 + 0] - svel[pj * 2 + 0];
        float vy = svel[pi * 2 + 1] - svel[pj * 2 + 1];
        float dn = sqrtf(rx * rx + ry * ry + 1e-8f) * (1.0f / 1024.0f);
        float f[6] = {rx * (1.0f / 1024.0f), ry * (1.0f / 1024.0f), vx, vy, dn, 1.0f / (1.0f + dn)};
        const float* W1 = (const float*)a.in[I_TW1];
        const float* B1 = (const float*)a.in[I_TB1];
        #pragma unroll
        for (int g = 0; g < 8; g++) {
            float v[8];
            #pragma unroll
            for (int e = 0; e < 8; e++) v[e] = B1[g * 8 + e];
            #pragma unroll
            for (int kk = 0; kk < 6; kk++)
                #pragma unroll
                for (int e = 0; e < 8; e++) v[e] = fmaf(f[kk], W1[kk * 64 + g * 8 + e], v[e]);
            #pragma unroll
            for (int e = 0; e < 8; e++) v[e] = v[e] * sigm(v[e]);
            uint4 pk;
            pk.x = pack2f(v[0], v[1]); pk.y = pack2f(v[2], v[3]);
            pk.z = pack2f(v[4], v[5]); pk.w = pack2f(v[6], v[7]);
            *(uint4*)&sR1[t * 64 + ((g ^ (t & 7)) << 3)] = pk;
        }
    }
    __syncthreads();

    // -------- P3b: trunk2 (64->64) MFMA, in place (wave-local rows, swizzled) --------
    {
        short8 taf[4][2];
        #pragma unroll
        for (int mi = 0; mi < 4; mi++)
            #pragma unroll
            for (int ks = 0; ks < 2; ks++) {
                int R = colw + mi * 16 + l15;
                taf[mi][ks] = ld_u4(&sR1[R * 64 + (((ks * 4 + quad) ^ (R & 7)) << 3)]);
            }
        floatx4 tacc[4][4] = {};
        #pragma unroll
        for (int ks = 0; ks < 2; ks++) {
            short8 bf[4];
            #pragma unroll
            for (int nj = 0; nj < 4; nj++)
                bf[nj] = UW ? ld_bws(ws + OFF_TW2, 2048, ks, nj * 16, l15, quad)
                            : ld_bf32((const float*)a.in[I_TW2], 64, 64, ks, nj * 16, l15, quad);
            #pragma unroll
            for (int mi = 0; mi < 4; mi++)
                #pragma unroll
                for (int nj = 0; nj < 4; nj++)
                    tacc[mi][nj] = __builtin_amdgcn_mfma_f32_16x16x32_bf16(taf[mi][ks], bf[nj], tacc[mi][nj], 0, 0, 0);
        }
        const float* B2 = (const float*)a.in[I_TB2];
        #pragma unroll
        for (int nj = 0; nj < 4; nj++) {
            int c = nj * 16 + l15;
            float bb = B2[c];
            #pragma unroll
            for (int mi = 0; mi < 4; mi++)
                #pragma unroll
                for (int r = 0; r < 4; r++) {
                    int row = colw + mi * 16 + quad * 4 + r;
                    sR1[TRK(row, c)] = f2bf(tacc[mi][nj][r] + bb);
                }
        }
    }
    __syncthreads();

    // -------- P3c: adapt (64->32) -> bias tmp (R2) -> bias regs --------
    {
        floatx4 tacc[4][2] = {};
        #pragma unroll
        for (int ks = 0; ks < 2; ks++) {
            short8 bf[2];
            #pragma unroll
            for (int nj = 0; nj < 2; nj++) {
                if (UW) bf[nj] = ld_bws(ws + OFF_ADW, 1024, ks, nj * 16, l15, quad);
                else {
                    const float* adw = (const float*)a.in[I_ADW];
                    int n = nj * 16 + l15;
                    #pragma unroll
                    for (int j = 0; j < 8; j++) {
                        int k = ks * 32 + quad * 8 + j;
                        bf[nj][j] = (short)f2bf(k < 64 ? adw[((n >> 3) * 64 + k) * 8 + (n & 7)] : 0.0f);
                    }
                }
            }
            #pragma unroll
            for (int mi = 0; mi < 4; mi++) {
                int R = colw + mi * 16 + l15;
                short8 af = ld_u4(&sR1[R * 64 + (((ks * 4 + quad) ^ (R & 7)) << 3)]);
                #pragma unroll
                for (int nj = 0; nj < 2; nj++)
                    tacc[mi][nj] = __builtin_amdgcn_mfma_f32_16x16x32_bf16(af, bf[nj], tacc[mi][nj], 0, 0, 0);
            }
        }
        const float* adb = (const float*)a.in[I_ADB];
        #pragma unroll
        for (int nj = 0; nj < 2; nj++) {
            int n = nj * 16 + l15;
            float bb = adb[n];
            #pragma unroll
            for (int mi = 0; mi < 4; mi++)
                #pragma unroll
                for (int r = 0; r < 4; r++) {
                    int pl = mi * 16 + quad * 4 + r;   // pair idx within token (wave = token)
                    sR2[((w * 4 + (n >> 3)) * 8 + (n & 7)) * 64 + pl] = f2bf(tacc[mi][nj][r] + bb);
                }
        }
        __syncthreads();
        // extract per-lane bias regs: for (layer, unit) 4 consecutive j values
        int tk = 2 * p + (quad >> 1);
        #pragma unroll
        for (int l = 0; l < NL; l++)
            #pragma unroll
            for (int u = 0; u < 4; u++) {
                int base = ((tk * 4 + l) * 8 + (h0 + u)) * 64 + (l15 & 7) * 8 + (quad & 1) * 4;
                const u32* bp = (const u32*)&sR2[base];
                br[l][u][0] = bp[0];
                br[l][u][1] = bp[1];
            }
    }
    __syncthreads();   // bias reads done; R2 free for nx

    // -------- P4: layers (UNROLLED so br/xr stay in VGPRs) --------
    const float* normw = (const float*)a.in[I_NORMW];
    const bool qvalid = ((quad >> 1) == (l15 >> 3));
    #pragma unroll
    for (int l = 0; l < NL; l++) {
        // (a) rms
        float invr[8];
        {
            float ssv[8];
            #pragma unroll
            for (int mi = 0; mi < 2; mi++)
                #pragma unroll
                for (int r = 0; r < 4; r++) {
                    float s = 0.0f;
                    #pragma unroll
                    for (int nj = 0; nj < 4; nj++) { float v = xr[mi][nj][r]; s = fmaf(v, v, s); }
                    ssv[mi * 4 + r] = s;
                }
            #pragma unroll
            for (int m = 1; m < 16; m <<= 1)
                #pragma unroll
                for (int k2 = 0; k2 < 8; k2++) ssv[k2] += __shfl_xor(ssv[k2], m);
            if (l15 == 0) {
                #pragma unroll
                for (int mi = 0; mi < 2; mi++)
                    #pragma unroll
                    for (int r = 0; r < 4; r++)
                        sred[(mi * 16 + quad * 4 + r) * 4 + w] = ssv[mi * 4 + r];
            }
            __syncthreads();
            #pragma unroll
            for (int mi = 0; mi < 2; mi++)
                #pragma unroll
                for (int r = 0; r < 4; r++) {
                    int row = mi * 16 + quad * 4 + r;
                    float s = sred[row * 4 + 0] + sred[row * 4 + 1] + sred[row * 4 + 2] + sred[row * 4 + 3];
                    invr[mi * 4 + r] = rsqrtf(s * (1.0f / 256.0f) + 1e-6f);
                }
        }
        // (b) nx -> R2
        {
            #pragma unroll
            for (int nj = 0; nj < 4; nj++) {
                int c = colw + nj * 16 + l15;
                float nwv = normw[l * 256 + c];
                #pragma unroll
                for (int mi = 0; mi < 2; mi++)
                    #pragma unroll
                    for (int r = 0; r < 4; r++)
                        sR2[(mi * 16 + quad * 4 + r) * 264 + c] = f2bf(xr[mi][nj][r] * invr[mi * 4 + r] * nwv);
            }
        }
        __syncthreads();

        // (c) Q, K projections (stores to R1 overlap other waves' nx reads safely)
        {
            floatx4 acc[2][4] = {};
            gemm32<UW>(sR2, ws + OFF_QKVO + (l * 4 + 0) * 65536, (const float*)a.in[I_WQ] + l * 65536, 8, 256, colw, l15, quad, acc);
            const float* bq = (const float*)a.in[I_BQ] + l * 256;
            #pragma unroll
            for (int nj = 0; nj < 4; nj++) {
                int c = colw + nj * 16 + l15;
                float bb = bq[c];
                #pragma unroll
                for (int mi = 0; mi < 2; mi++)
                    #pragma unroll
                    for (int r = 0; r < 4; r++)
                        sR1[(mi * 16 + quad * 4 + r) * 264 + c] = f2bf((acc[mi][nj][r] + bb) * 0.17677669529663689f);
            }
        }
        {
            floatx4 acc[2][4] = {};
            gemm32<UW>(sR2, ws + OFF_QKVO + (l * 4 + 1) * 65536, (const float*)a.in[I_WK] + l * 65536, 8, 256, colw, l15, quad, acc);
            const float* bk = (const float*)a.in[I_BK] + l * 256;
            #pragma unroll
            for (int nj = 0; nj < 4; nj++) {
                int c = colw + nj * 16 + l15;
                float bb = bk[c];
                #pragma unroll
                for (int mi = 0; mi < 2; mi++)
                    #pragma unroll
                    for (int r = 0; r < 4; r++)
                        skb[(mi * 16 + quad * 4 + r) * 264 + c] = f2bf(acc[mi][nj][r] + bb);
            }
        }
        // V projection; store must wait for all waves' nx reads
        {
            floatx4 acc[2][4] = {};
            gemm32<UW>(sR2, ws + OFF_QKVO + (l * 4 + 2) * 65536, (const float*)a.in[I_WV] + l * 65536, 8, 256, colw, l15, quad, acc);
            __syncthreads();
            const float* bv = (const float*)a.in[I_BV] + l * 256;
            #pragma unroll
            for (int nj = 0; nj < 4; nj++) {
                int c = colw + nj * 16 + l15;
                float bb = bv[c];
                #pragma unroll
                for (int mi = 0; mi < 2; mi++)
                    #pragma unroll
                    for (int r = 0; r < 4; r++)
                        sR2[(mi * 16 + quad * 4 + r) * 264 + c] = f2bf(acc[mi][nj][r] + bb);
            }
        }
        __syncthreads();   // q, k, v visible

        // (d/e) MFMA attention: 4 units (pair p, head h0+u); O overwrites q (disjoint cols)
        #pragma unroll
        for (int u = 0; u < 4; u++) {
            int h = h0 + u;
            short8 kf = ld_u4(&skb[(p * 16 + l15) * 264 + h * 32 + quad * 8]);
            short8 qf = ld_u4(&sR1[(p * 16 + l15) * 264 + h * 32 + quad * 8]);
            floatx4 zero = {};
            floatx4 st = __builtin_amdgcn_mfma_f32_16x16x32_bf16(kf, qf, zero, 0, 0, 0);
            float bb[4];
            unpack2(br[l][u][0], bb[0], bb[1]);
            unpack2(br[l][u][1], bb[2], bb[3]);
            float s[4];
            #pragma unroll
            for (int r = 0; r < 4; r++) {
                int jl = (quad & 1) * 4 + r;
                bool alv = (amask >> jl) & 1;
                s[r] = qvalid ? (alv ? st[r] + bb[r] : -1.0e9f) : -2.0e9f;
            }
            float mx = fmaxf(fmaxf(s[0], s[1]), fmaxf(s[2], s[3]));
            mx = fmaxf(mx, __shfl_xor(mx, 16));
            mx = fmaxf(mx, __shfl_xor(mx, 32));
            float e[4], sm = 0.0f;
            #pragma unroll
            for (int r = 0; r < 4; r++) { e[r] = __expf(s[r] - mx); sm += e[r]; }
            sm += __shfl_xor(sm, 16);
            sm += __shfl_xor(sm, 32);
            float inv = 1.0f / sm;
            u32 u01 = pack2f(e[0] * inv, e[1] * inv);
            u32 u23 = pack2f(e[2] * inv, e[3] * inv);
            // redistribute P^T lanes into PV A-frag (k = quad*8 + jj)
            int srcA = (quad * 32 + l15) & 63;
            u32 a0 = (u32)__shfl((int)u01, srcA);
            u32 a1 = (u32)__shfl((int)u23, srcA);
            u32 a2 = (u32)__shfl((int)u01, (srcA + 16) & 63);
            u32 a3 = (u32)__shfl((int)u23, (srcA + 16) & 63);
            if (quad >= 2) { a0 = 0; a1 = 0; a2 = 0; a3 = 0; }
            union { u32 uu[4]; short8 ss; } cv;
            cv.uu[0] = a0; cv.uu[1] = a1; cv.uu[2] = a2; cv.uu[3] = a3;
            short8 paf = cv.ss;
            #pragma unroll
            for (int nt = 0; nt < 2; nt++) {
                short8 vf;
                if (quad < 2) {
                    #pragma unroll
                    for (int jj = 0; jj < 8; jj++) {
                        int kr = quad * 8 + jj;
                        vf[jj] = (short)sR2[(p * 16 + kr) * 264 + h * 32 + nt * 16 + l15];
                    }
                } else {
                    #pragma unroll
                    for (int jj = 0; jj < 8; jj++) vf[jj] = 0;
                }
                floatx4 z2 = {};
                floatx4 o = __builtin_amdgcn_mfma_f32_16x16x32_bf16(paf, vf, z2, 0, 0, 0);
                #pragma unroll
                for (int r = 0; r < 4; r++)
                    sR1[(p * 16 + quad * 4 + r) * 264 + h * 32 + nt * 16 + l15] = f2bf(o[r]);
            }
        }
        __syncthreads();   // O visible

        // (f) x += O @ Wo + bo
        {
            floatx4 acc[2][4] = {};
            gemm32<UW>(sR1, ws + OFF_QKVO + (l * 4 + 3) * 65536, (const float*)a.in[I_WO] + l * 65536,
                       8, 256, colw, l15, quad, acc);
            const float* bo = (const float*)a.in[I_BO] + l * 256;
            #pragma unroll
            for (int nj = 0; nj < 4; nj++) {
                float bb = bo[colw + nj * 16 + l15];
                #pragma unroll
                for (int mi = 0; mi < 2; mi++)
                    #pragma unroll
                    for (int r = 0; r < 4; r++)
                        xr[mi][nj][r] += acc[mi][nj][r] + bb;
            }
        }
        __syncthreads();   // O reads done before next layer / head staging
    }

    // -------- P5: stage x -> R1 fp32, then head (256 -> 12) --------
    {
        float* xf = (float*)sR1;
        #pragma unroll
        for (int nj = 0; nj < 4; nj++) {
            int c = colw + nj * 16 + l15;
            #pragma unroll
            for (int mi = 0; mi < 2; mi++)
                #pragma unroll
                for (int r = 0; r < 4; r++)
                    xf[(mi * 16 + quad * 4 + r) * 264 + c] = xr[mi][nj][r];
        }
        __syncthreads();
        int row = t >> 3, pp = t & 7;
        const float* HW = (const float*)a.in[I_HW];
        float ah[12];
        #pragma unroll
        for (int c = 0; c < 12; c++) ah[c] = 0.0f;
        for (int kk = pp * 32; kk < pp * 32 + 32; kk++) {
            float xv = xf[row * 264 + kk];
            #pragma unroll
            for (int c = 0; c < 12; c++) ah[c] = fmaf(xv, HW[kk * 12 + c], ah[c]);
        }
        #pragma unroll
        for (int c = 0; c < 12; c++) {
            ah[c] += __shfl_xor(ah[c], 1);
            ah[c] += __shfl_xor(ah[c], 2);
            ah[c] += __shfl_xor(ah[c], 4);
        }
        if (pp == 0) {
            const float* hb = (const float*)a.in[I_HB];
            #pragma unroll
            for (int c = 0; c < 12; c++)
                a.out[(bid * MROWS + row) * AD + c] = ah[c] + hb[c];
        }
    }
}

extern "C" void kernel_launch(void* const* d_in, const int* in_sizes, int n_in,
                              void* d_out, int out_size, void* d_ws, size_t ws_size,
                              hipStream_t stream) {
    (void)in_sizes; (void)n_in; (void)out_size;
    Args a;
    for (int i = 0; i < N_IN; i++) a.in[i] = d_in[i];
    a.out = (float*)d_out;
    u16* ws16 = (u16*)d_ws;
    const bool use_ws = (ws_size >= (size_t)WS_BYTES) && (d_ws != nullptr);
    if (use_ws) {
        hipLaunchKernelGGL(prep_kernel, dim3(256, 20), dim3(256), 0, stream, a, ws16);
        hipFuncSetAttribute((const void*)yemong_mfma<true>, hipFuncAttributeMaxDynamicSharedMemorySize, SMEM_BYTES);
        hipLaunchKernelGGL((yemong_mfma<true>), dim3(NBLK), dim3(256), SMEM_BYTES, stream, a, ws16);
    } else {
        hipFuncSetAttribute((const void*)yemong_mfma<false>, hipFuncAttributeMaxDynamicSharedMemorySize, SMEM_BYTES);
        hipLaunchKernelGGL((yemong_mfma<false>), dim3(NBLK), dim3(256), SMEM_BYTES, stream, a, ws16);
    }
}

// Round 8
// 1133.819 us; speedup vs baseline: 1.1459x; 1.0734x over previous
//
#include <hip/hip_runtime.h>
#include <cstdint>

#define DEV __device__ __forceinline__

typedef __attribute__((ext_vector_type(8))) short short8;
typedef __attribute__((ext_vector_type(4))) float floatx4;
typedef unsigned short u16;
typedef unsigned int u32;

DEV u16 f2bf(float f) {
    unsigned u = __float_as_uint(f);
    return (u16)((u + 0x7fffu + ((u >> 16) & 1u)) >> 16);  // RNE
}
DEV void unpack2(u32 u, float& a, float& b) {
    a = __uint_as_float(u << 16);
    b = __uint_as_float(u & 0xffff0000u);
}
DEV u32 pack2f(float a, float b) { return (u32)f2bf(a) | ((u32)f2bf(b) << 16); }
DEV float sigm(float x) { return 1.0f / (1.0f + __expf(-x)); }

// Problem constants
#define NAG 8
#define DM 256
#define NL 4
#define AD 12
#define MROWS 32
#define NBLK 4096

// ws (bf16 units) offsets: weights in MFMA B-frag order [ks][n][quad][j]
#define OFF_E1   0
#define OFF_E2   8192
#define OFF_QKVO 73728        // 16 matrices of 65536: (l*4+m), m: 0=q 1=k 2=v 3=o
#define OFF_TW2  1122304
#define OFF_ADW  1126400
#define WS_TOTAL 1128448
#define WS_BYTES (WS_TOTAL * 2)

// dynamic LDS (bytes), total 51712
#define L_R1    0         // 33792: q[32][264]u16 @0 + k @16896 | trunk swizzled [256][64]u16 | head-x fp32 [32][264]
#define L_R2    33792     // 16896: state/nx/V [32][264]u16 ; bias tmp bf16 [4tok][4l][8h][64]
#define L_RED   50688     // 512: rms partials fp32 [32][4]
#define L_SPOS  51200     // 256
#define L_SVEL  51456     // 256
#define SMEM_BYTES 51712

// trunk swizzle: element (row, col) -> row*64 + ((col>>3 ^ (row&7))<<3) + (col&7)
#define TRK(row, col) ((row) * 64 + ((((col) >> 3) ^ ((row) & 7)) << 3) + ((col) & 7))

enum { I_STATE=0, I_POS, I_VEL, I_TEAM, I_ALIVE, I_DEAD, I_EW1, I_EB1, I_EW2, I_EB2,
       I_TEMB, I_SEMB, I_TW1, I_TB1, I_TW2, I_TB2, I_ADW, I_ADB, I_NORMW,
       I_WQ, I_BQ, I_WK, I_BK, I_WV, I_BV, I_WO, I_BO, I_HW, I_HB, N_IN };

struct Args { const void* in[N_IN]; float* out; };

// ---------------- weight pre-conversion: fp32 [K][N] -> bf16 frag order ----------------
__global__ __launch_bounds__(256) void prep_kernel(Args a, u16* ws)
{
    int e = blockIdx.x * 256 + threadIdx.x;
    int mat = blockIdx.y;
    int size, offs, N, Kreal;
    const float* src;
    if (mat == 0)      { size = 8192;  offs = OFF_E1;  N = 256; Kreal = 16;  src = (const float*)a.in[I_EW1]; }
    else if (mat == 1) { size = 65536; offs = OFF_E2;  N = 256; Kreal = 256; src = (const float*)a.in[I_EW2]; }
    else if (mat < 18) {
        int q = mat - 2, l = q >> 2, m = q & 3;
        int wi = (m == 0) ? I_WQ : (m == 1) ? I_WK : (m == 2) ? I_WV : I_WO;
        size = 65536; offs = OFF_QKVO + q * 65536; N = 256; Kreal = 256;
        src = (const float*)a.in[wi] + l * 65536;
    }
    else if (mat == 18) { size = 4096; offs = OFF_TW2; N = 64; Kreal = 64; src = (const float*)a.in[I_TW2]; }
    else                { size = 2048; offs = OFF_ADW; N = 32; Kreal = 64; src = (const float*)a.in[I_ADW]; }
    if (e >= size) return;
    int ksblk = N * 32;
    int ks = e / ksblk, rem = e % ksblk;
    int n = rem >> 5, quad = (rem >> 3) & 3, j = rem & 7;
    int k = ks * 32 + quad * 8 + j;
    float v = 0.0f;
    if (k < Kreal) {
        if (mat == 19) v = src[((n >> 3) * 64 + k) * 8 + (n & 7)];   // adapt_W[l][k][h], n=l*8+h
        else           v = src[k * N + n];
    }
    ws[offs + e] = f2bf(v);
}

// ---------------- MFMA fragment loaders ----------------
DEV short8 ld_u4(const u16* p) {
    union { uint4 u; short8 s; } c;
    c.u = *(const uint4*)p;
    return c.s;
}
DEV short8 ld_afrag(const u16* A, int stride, int row0, int kofs, int l15, int quad) {
    return ld_u4(A + (row0 + l15) * stride + kofs + quad * 8);
}
DEV short8 ld_bws(const u16* w, int ksblk, int ks, int col, int l15, int quad) {
    return ld_u4(w + ks * ksblk + (col + l15) * 32 + quad * 8);
}
DEV short8 ld_bf32(const float* W, int N, int Kreal, int ks, int col, int l15, int quad) {
    short8 r;
    #pragma unroll
    for (int j = 0; j < 8; j++) {
        int k = ks * 32 + quad * 8 + j;
        float v = (k < Kreal) ? W[k * N + col + l15] : 0.0f;
        r[j] = (short)f2bf(v);
    }
    return r;
}

// M=32 GEMM: A [32][264] bf16 LDS, wave covers cols [colw, colw+64)
template<bool UW>
DEV void gemm32(const u16* A, const u16* wsW, const float* Wf,
                int Kb, int Kreal, int colw, int l15, int quad, floatx4 acc[2][4]) {
    for (int ks = 0; ks < Kb; ks++) {
        short8 af0 = ld_afrag(A, 264, 0,  ks * 32, l15, quad);
        short8 af1 = ld_afrag(A, 264, 16, ks * 32, l15, quad);
        short8 bf[4];
        #pragma unroll
        for (int nj = 0; nj < 4; nj++)
            bf[nj] = UW ? ld_bws(wsW, 8192, ks, colw + nj * 16, l15, quad)
                        : ld_bf32(Wf, 256, Kreal, ks, colw + nj * 16, l15, quad);
        #pragma unroll
        for (int nj = 0; nj < 4; nj++) {
            acc[0][nj] = __builtin_amdgcn_mfma_f32_16x16x32_bf16(af0, bf[nj], acc[0][nj], 0, 0, 0);
            acc[1][nj] = __builtin_amdgcn_mfma_f32_16x16x32_bf16(af1, bf[nj], acc[1][nj], 0, 0, 0);
        }
    }
}

template<bool UW>
__global__ __launch_bounds__(256, 2) void yemong_mfma(Args a, const u16* ws)
{
    extern __shared__ char smem[];
    u16* sR1   = (u16*)(smem + L_R1);     // q / trunk / head-x
    u16* skb   = (u16*)(smem + L_R1 + 16896);  // k
    u16* sR2   = (u16*)(smem + L_R2);     // state / nx / V / bias-tmp
    float* sred = (float*)(smem + L_RED);
    float* spos = (float*)(smem + L_SPOS);
    float* svel = (float*)(smem + L_SVEL);

    const int t = threadIdx.x, bid = blockIdx.x;
    const int lane = t & 63, w = t >> 6;
    const int l15 = lane & 15, quad = lane >> 4;
    const int colw = w * 64;
    const int p = w >> 1, h0 = (w & 1) * 4;   // attention pair / head base

    float xr[2][4][4];        // residual x (C-layout): row=mi*16+quad*4+r, col=colw+nj*16+l15
    u32 br[NL][4][2];         // attn bias, packed bf16 x4 per (layer, unit)
    u32 amask;                // alive bits of this lane's attention token

    // alive-layout probe (byte bools vs int32 bools), uniform
    unsigned mp = 0;
    const unsigned* au = (const unsigned*)a.in[I_ALIVE];
    #pragma unroll
    for (int i = 0; i < 16; i++) mp |= au[i];
    const bool abyte = (mp > 1u);
    auto aliveAt = [&](int r) -> int {
        int gi = bid * MROWS + r;
        return abyte ? (int)((const unsigned char*)a.in[I_ALIVE])[gi]
                     : ((const int*)a.in[I_ALIVE])[gi];
    };

    // -------- P0: metadata + masked state staging --------
    if (t < 64) {
        int n = t >> 1, d = t & 1;
        spos[n * 2 + d] = ((const float*)a.in[I_POS])[(bid * MROWS + n) * 2 + d] * 1024.0f;
        svel[n * 2 + d] = ((const float*)a.in[I_VEL])[(bid * MROWS + n) * 2 + d];
    }
    {
        int tk = 2 * p + (quad >> 1);
        amask = 0;
        #pragma unroll
        for (int j = 0; j < 8; j++) amask |= (aliveAt(tk * 8 + j) ? 1u : 0u) << j;
    }
    {
        const float* gs = (const float*)a.in[I_STATE];
        const float* gd = (const float*)a.in[I_DEAD];
        #pragma unroll
        for (int it = 0; it < 4; it++) {
            int idx = t + 256 * it;              // 32 rows x 32 k
            int r = idx >> 5, kk = idx & 31;
            float v = 0.0f;
            if (kk < 16) v = aliveAt(r) ? gs[(bid * MROWS + r) * 16 + kk] : gd[kk];
            sR2[r * 264 + kk] = f2bf(v);
        }
    }
    __syncthreads();

    // -------- P1: enc1 (16->256) + silu, in place over R2 --------
    {
        floatx4 acc[2][4] = {};
        gemm32<UW>(sR2, ws + OFF_E1, (const float*)a.in[I_EW1], 1, 16, colw, l15, quad, acc);
        __syncthreads();
        const float* b1 = (const float*)a.in[I_EB1];
        #pragma unroll
        for (int nj = 0; nj < 4; nj++) {
            int c = colw + nj * 16 + l15;
            float bb = b1[c];
            #pragma unroll
            for (int mi = 0; mi < 2; mi++)
                #pragma unroll
                for (int r = 0; r < 4; r++) {
                    float v = acc[mi][nj][r] + bb;
                    sR2[(mi * 16 + quad * 4 + r) * 264 + c] = f2bf(v * sigm(v));
                }
        }
    }
    __syncthreads();

    // -------- P2: enc2 (256->256) + b2 + embeddings -> xr --------
    {
        floatx4 acc[2][4] = {};
        gemm32<UW>(sR2, ws + OFF_E2, (const float*)a.in[I_EW2], 8, 256, colw, l15, quad, acc);
        const float* b2 = (const float*)a.in[I_EB2];
        const float* te = (const float*)a.in[I_TEMB];
        const float* se = (const float*)a.in[I_SEMB];
        const int* gteam = (const int*)a.in[I_TEAM];
        int team8[8];
        #pragma unroll
        for (int mi = 0; mi < 2; mi++)
            #pragma unroll
            for (int r = 0; r < 4; r++)
                team8[mi * 4 + r] = gteam[bid * MROWS + mi * 16 + quad * 4 + r];
        #pragma unroll
        for (int nj = 0; nj < 4; nj++) {
            int c = colw + nj * 16 + l15;
            float bb = b2[c];
            #pragma unroll
            for (int mi = 0; mi < 2; mi++)
                #pragma unroll
                for (int r = 0; r < 4; r++) {
                    int row = mi * 16 + quad * 4 + r;
                    xr[mi][nj][r] = acc[mi][nj][r] + bb + te[team8[mi * 4 + r] * 256 + c] + se[(row & 7) * 256 + c];
                }
        }
    }

    // -------- P3a: pair features + trunk1 (6->64) + silu -> swizzled trunk [256][64] --------
    {
        int tokp = t >> 6;
        int pi = tokp * 8 + ((t >> 3) & 7), pj = tokp * 8 + (t & 7);
        float rx = spos[pi * 2 + 0] - spos[pj * 2 + 0];
        float ry = spos[pi * 2 + 1] - spos[pj * 2 + 1];
        rx -= rintf(rx * (1.0f / 1024.0f)) * 1024.0f;
        ry -= rintf(ry * (1.0f / 1024.0f)) * 1024.0f;
        float vx = svel[pi * 2 + 0] - svel[pj * 2 + 0];
        float vy = svel[pi * 2 + 1] - svel[pj * 2 + 1];
        float dn = sqrtf(rx * rx + ry * ry + 1e-8f) * (1.0f / 1024.0f);
        float f[6] = {rx * (1.0f / 1024.0f), ry * (1.0f / 1024.0f), vx, vy, dn, 1.0f / (1.0f + dn)};
        const float* W1 = (const float*)a.in[I_TW1];
        const float* B1 = (const float*)a.in[I_TB1];
        #pragma unroll
        for (int g = 0; g < 8; g++) {
            float v[8];
            #pragma unroll
            for (int e = 0; e < 8; e++) v[e] = B1[g * 8 + e];
            #pragma unroll
            for (int kk = 0; kk < 6; kk++)
                #pragma unroll
                for (int e = 0; e < 8; e++) v[e] = fmaf(f[kk], W1[kk * 64 + g * 8 + e], v[e]);
            #pragma unroll
            for (int e = 0; e < 8; e++) v[e] = v[e] * sigm(v[e]);
            uint4 pk;
            pk.x = pack2f(v[0], v[1]); pk.y = pack2f(v[2], v[3]);
            pk.z = pack2f(v[4], v[5]); pk.w = pack2f(v[6], v[7]);
            *(uint4*)&sR1[t * 64 + ((g ^ (t & 7)) << 3)] = pk;
        }
    }
    __syncthreads();

    // -------- P3b: trunk2 (64->64) MFMA, in place (wave-local rows, swizzled) --------
    {
        short8 taf[4][2];
        #pragma unroll
        for (int mi = 0; mi < 4; mi++)
            #pragma unroll
            for (int ks = 0; ks < 2; ks++) {
                int R = colw + mi * 16 + l15;
                taf[mi][ks] = ld_u4(&sR1[R * 64 + (((ks * 4 + quad) ^ (R & 7)) << 3)]);
            }
        floatx4 tacc[4][4] = {};
        #pragma unroll
        for (int ks = 0; ks < 2; ks++) {
            short8 bf[4];
            #pragma unroll
            for (int nj = 0; nj < 4; nj++)
                bf[nj] = UW ? ld_bws(ws + OFF_TW2, 2048, ks, nj * 16, l15, quad)
                            : ld_bf32((const float*)a.in[I_TW2], 64, 64, ks, nj * 16, l15, quad);
            #pragma unroll
            for (int mi = 0; mi < 4; mi++)
                #pragma unroll
                for (int nj = 0; nj < 4; nj++)
                    tacc[mi][nj] = __builtin_amdgcn_mfma_f32_16x16x32_bf16(taf[mi][ks], bf[nj], tacc[mi][nj], 0, 0, 0);
        }
        const float* B2 = (const float*)a.in[I_TB2];
        #pragma unroll
        for (int nj = 0; nj < 4; nj++) {
            int c = nj * 16 + l15;
            float bb = B2[c];
            #pragma unroll
            for (int mi = 0; mi < 4; mi++)
                #pragma unroll
                for (int r = 0; r < 4; r++) {
                    int row = colw + mi * 16 + quad * 4 + r;
                    sR1[TRK(row, c)] = f2bf(tacc[mi][nj][r] + bb);
                }
        }
    }
    __syncthreads();

    // -------- P3c: adapt (64->32) -> bias tmp (R2) -> bias regs --------
    {
        floatx4 tacc[4][2] = {};
        #pragma unroll
        for (int ks = 0; ks < 2; ks++) {
            short8 bf[2];
            #pragma unroll
            for (int nj = 0; nj < 2; nj++) {
                if (UW) bf[nj] = ld_bws(ws + OFF_ADW, 1024, ks, nj * 16, l15, quad);
                else {
                    const float* adw = (const float*)a.in[I_ADW];
                    int n = nj * 16 + l15;
                    #pragma unroll
                    for (int j = 0; j < 8; j++) {
                        int k = ks * 32 + quad * 8 + j;
                        bf[nj][j] = (short)f2bf(k < 64 ? adw[((n >> 3) * 64 + k) * 8 + (n & 7)] : 0.0f);
                    }
                }
            }
            #pragma unroll
            for (int mi = 0; mi < 4; mi++) {
                int R = colw + mi * 16 + l15;
                short8 af = ld_u4(&sR1[R * 64 + (((ks * 4 + quad) ^ (R & 7)) << 3)]);
                #pragma unroll
                for (int nj = 0; nj < 2; nj++)
                    tacc[mi][nj] = __builtin_amdgcn_mfma_f32_16x16x32_bf16(af, bf[nj], tacc[mi][nj], 0, 0, 0);
            }
        }
        const float* adb = (const float*)a.in[I_ADB];
        #pragma unroll
        for (int nj = 0; nj < 2; nj++) {
            int n = nj * 16 + l15;
            float bb = adb[n];
            #pragma unroll
            for (int mi = 0; mi < 4; mi++)
                #pragma unroll
                for (int r = 0; r < 4; r++) {
                    int pl = mi * 16 + quad * 4 + r;   // pair idx within token (wave = token)
                    sR2[((w * 4 + (n >> 3)) * 8 + (n & 7)) * 64 + pl] = f2bf(tacc[mi][nj][r] + bb);
                }
        }
        __syncthreads();
        // extract per-lane bias regs: for (layer, unit) 4 consecutive j values
        int tk = 2 * p + (quad >> 1);
        #pragma unroll
        for (int l = 0; l < NL; l++)
            #pragma unroll
            for (int u = 0; u < 4; u++) {
                int base = ((tk * 4 + l) * 8 + (h0 + u)) * 64 + (l15 & 7) * 8 + (quad & 1) * 4;
                const u32* bp = (const u32*)&sR2[base];
                br[l][u][0] = bp[0];
                br[l][u][1] = bp[1];
            }
    }
    __syncthreads();   // bias reads done; R2 free for nx

    // -------- P4: layers (unrolled; xr/br stay in VGPRs at budget 256) --------
    const float* normw = (const float*)a.in[I_NORMW];
    const bool qvalid = ((quad >> 1) == (l15 >> 3));
    #pragma unroll
    for (int l = 0; l < NL; l++) {
        // (a) rms
        float invr[8];
        {
            float ssv[8];
            #pragma unroll
            for (int mi = 0; mi < 2; mi++)
                #pragma unroll
                for (int r = 0; r < 4; r++) {
                    float s = 0.0f;
                    #pragma unroll
                    for (int nj = 0; nj < 4; nj++) { float v = xr[mi][nj][r]; s = fmaf(v, v, s); }
                    ssv[mi * 4 + r] = s;
                }
            #pragma unroll
            for (int m = 1; m < 16; m <<= 1)
                #pragma unroll
                for (int k2 = 0; k2 < 8; k2++) ssv[k2] += __shfl_xor(ssv[k2], m);
            if (l15 == 0) {
                #pragma unroll
                for (int mi = 0; mi < 2; mi++)
                    #pragma unroll
                    for (int r = 0; r < 4; r++)
                        sred[(mi * 16 + quad * 4 + r) * 4 + w] = ssv[mi * 4 + r];
            }
            __syncthreads();
            #pragma unroll
            for (int mi = 0; mi < 2; mi++)
                #pragma unroll
                for (int r = 0; r < 4; r++) {
                    int row = mi * 16 + quad * 4 + r;
                    float s = sred[row * 4 + 0] + sred[row * 4 + 1] + sred[row * 4 + 2] + sred[row * 4 + 3];
                    invr[mi * 4 + r] = rsqrtf(s * (1.0f / 256.0f) + 1e-6f);
                }
        }
        // (b) nx -> R2
        {
            #pragma unroll
            for (int nj = 0; nj < 4; nj++) {
                int c = colw + nj * 16 + l15;
                float nwv = normw[l * 256 + c];
                #pragma unroll
                for (int mi = 0; mi < 2; mi++)
                    #pragma unroll
                    for (int r = 0; r < 4; r++)
                        sR2[(mi * 16 + quad * 4 + r) * 264 + c] = f2bf(xr[mi][nj][r] * invr[mi * 4 + r] * nwv);
            }
        }
        __syncthreads();

        // (c) fused Q/K/V projections (3x ILP over shared A-frags)
        {
            floatx4 acc[3][2][4] = {};
            const u16* wq  = ws + OFF_QKVO + (l * 4 + 0) * 65536;
            const u16* wk  = ws + OFF_QKVO + (l * 4 + 1) * 65536;
            const u16* wvv = ws + OFF_QKVO + (l * 4 + 2) * 65536;
            const float* fq = (const float*)a.in[I_WQ] + l * 65536;
            const float* fk = (const float*)a.in[I_WK] + l * 65536;
            const float* fv = (const float*)a.in[I_WV] + l * 65536;
            #pragma unroll 2
            for (int ks = 0; ks < 8; ks++) {
                short8 af0 = ld_afrag(sR2, 264, 0,  ks * 32, l15, quad);
                short8 af1 = ld_afrag(sR2, 264, 16, ks * 32, l15, quad);
                short8 bq[4], bk[4], bv[4];
                #pragma unroll
                for (int nj = 0; nj < 4; nj++) {
                    int c = colw + nj * 16;
                    bq[nj] = UW ? ld_bws(wq,  8192, ks, c, l15, quad) : ld_bf32(fq, 256, 256, ks, c, l15, quad);
                    bk[nj] = UW ? ld_bws(wk,  8192, ks, c, l15, quad) : ld_bf32(fk, 256, 256, ks, c, l15, quad);
                    bv[nj] = UW ? ld_bws(wvv, 8192, ks, c, l15, quad) : ld_bf32(fv, 256, 256, ks, c, l15, quad);
                }
                #pragma unroll
                for (int nj = 0; nj < 4; nj++) {
                    acc[0][0][nj] = __builtin_amdgcn_mfma_f32_16x16x32_bf16(af0, bq[nj], acc[0][0][nj], 0, 0, 0);
                    acc[0][1][nj] = __builtin_amdgcn_mfma_f32_16x16x32_bf16(af1, bq[nj], acc[0][1][nj], 0, 0, 0);
                    acc[1][0][nj] = __builtin_amdgcn_mfma_f32_16x16x32_bf16(af0, bk[nj], acc[1][0][nj], 0, 0, 0);
                    acc[1][1][nj] = __builtin_amdgcn_mfma_f32_16x16x32_bf16(af1, bk[nj], acc[1][1][nj], 0, 0, 0);
                    acc[2][0][nj] = __builtin_amdgcn_mfma_f32_16x16x32_bf16(af0, bv[nj], acc[2][0][nj], 0, 0, 0);
                    acc[2][1][nj] = __builtin_amdgcn_mfma_f32_16x16x32_bf16(af1, bv[nj], acc[2][1][nj], 0, 0, 0);
                }
            }
            // store q (scaled) and k
            const float* bqf = (const float*)a.in[I_BQ] + l * 256;
            const float* bkf = (const float*)a.in[I_BK] + l * 256;
            #pragma unroll
            for (int nj = 0; nj < 4; nj++) {
                int c = colw + nj * 16 + l15;
                float b0 = bqf[c], b1 = bkf[c];
                #pragma unroll
                for (int mi = 0; mi < 2; mi++)
                    #pragma unroll
                    for (int r = 0; r < 4; r++) {
                        int row = mi * 16 + quad * 4 + r;
                        sR1[row * 264 + c] = f2bf((acc[0][mi][nj][r] + b0) * 0.17677669529663689f);
                        skb[row * 264 + c] = f2bf(acc[1][mi][nj][r] + b1);
                    }
            }
            __syncthreads();    // all nx reads + q/k stores done
            const float* bvf = (const float*)a.in[I_BV] + l * 256;
            #pragma unroll
            for (int nj = 0; nj < 4; nj++) {
                int c = colw + nj * 16 + l15;
                float b2v = bvf[c];
                #pragma unroll
                for (int mi = 0; mi < 2; mi++)
                    #pragma unroll
                    for (int r = 0; r < 4; r++)
                        sR2[(mi * 16 + quad * 4 + r) * 264 + c] = f2bf(acc[2][mi][nj][r] + b2v);
            }
        }
        __syncthreads();   // q, k, v visible

        // (d/e) MFMA attention: 4 units (pair p, head h0+u); O overwrites q (disjoint cols)
        #pragma unroll
        for (int u = 0; u < 4; u++) {
            int h = h0 + u;
            short8 kf = ld_u4(&skb[(p * 16 + l15) * 264 + h * 32 + quad * 8]);
            short8 qf = ld_u4(&sR1[(p * 16 + l15) * 264 + h * 32 + quad * 8]);
            floatx4 zero = {};
            floatx4 st = __builtin_amdgcn_mfma_f32_16x16x32_bf16(kf, qf, zero, 0, 0, 0);
            float bb[4];
            unpack2(br[l][u][0], bb[0], bb[1]);
            unpack2(br[l][u][1], bb[2], bb[3]);
            float s[4];
            #pragma unroll
            for (int r = 0; r < 4; r++) {
                int jl = (quad & 1) * 4 + r;
                bool alv = (amask >> jl) & 1;
                s[r] = qvalid ? (alv ? st[r] + bb[r] : -1.0e9f) : -2.0e9f;
            }
            float mx = fmaxf(fmaxf(s[0], s[1]), fmaxf(s[2], s[3]));
            mx = fmaxf(mx, __shfl_xor(mx, 16));
            mx = fmaxf(mx, __shfl_xor(mx, 32));
            float e[4], sm = 0.0f;
            #pragma unroll
            for (int r = 0; r < 4; r++) { e[r] = __expf(s[r] - mx); sm += e[r]; }
            sm += __shfl_xor(sm, 16);
            sm += __shfl_xor(sm, 32);
            float inv = 1.0f / sm;
            u32 u01 = pack2f(e[0] * inv, e[1] * inv);
            u32 u23 = pack2f(e[2] * inv, e[3] * inv);
            // redistribute P^T lanes into PV A-frag (k = quad*8 + jj)
            int srcA = (quad * 32 + l15) & 63;
            u32 a0 = (u32)__shfl((int)u01, srcA);
            u32 a1 = (u32)__shfl((int)u23, srcA);
            u32 a2 = (u32)__shfl((int)u01, (srcA + 16) & 63);
            u32 a3 = (u32)__shfl((int)u23, (srcA + 16) & 63);
            if (quad >= 2) { a0 = 0; a1 = 0; a2 = 0; a3 = 0; }
            union { u32 uu[4]; short8 ss; } cv;
            cv.uu[0] = a0; cv.uu[1] = a1; cv.uu[2] = a2; cv.uu[3] = a3;
            short8 paf = cv.ss;
            #pragma unroll
            for (int nt = 0; nt < 2; nt++) {
                short8 vf;
                if (quad < 2) {
                    #pragma unroll
                    for (int jj = 0; jj < 8; jj++) {
                        int kr = quad * 8 + jj;
                        vf[jj] = (short)sR2[(p * 16 + kr) * 264 + h * 32 + nt * 16 + l15];
                    }
                } else {
                    #pragma unroll
                    for (int jj = 0; jj < 8; jj++) vf[jj] = 0;
                }
                floatx4 z2 = {};
                floatx4 o = __builtin_amdgcn_mfma_f32_16x16x32_bf16(paf, vf, z2, 0, 0, 0);
                #pragma unroll
                for (int r = 0; r < 4; r++)
                    sR1[(p * 16 + quad * 4 + r) * 264 + h * 32 + nt * 16 + l15] = f2bf(o[r]);
            }
        }
        __syncthreads();   // O visible

        // (f) x += O @ Wo + bo
        {
            floatx4 acc[2][4] = {};
            gemm32<UW>(sR1, ws + OFF_QKVO + (l * 4 + 3) * 65536, (const float*)a.in[I_WO] + l * 65536,
                       8, 256, colw, l15, quad, acc);
            const float* bo = (const float*)a.in[I_BO] + l * 256;
            #pragma unroll
            for (int nj = 0; nj < 4; nj++) {
                float bb = bo[colw + nj * 16 + l15];
                #pragma unroll
                for (int mi = 0; mi < 2; mi++)
                    #pragma unroll
                    for (int r = 0; r < 4; r++)
                        xr[mi][nj][r] += acc[mi][nj][r] + bb;
            }
        }
        __syncthreads();   // O reads done before next layer / head staging
    }

    // -------- P5: stage x -> R1 fp32, then head (256 -> 12) --------
    {
        float* xf = (float*)sR1;
        #pragma unroll
        for (int nj = 0; nj < 4; nj++) {
            int c = colw + nj * 16 + l15;
            #pragma unroll
            for (int mi = 0; mi < 2; mi++)
                #pragma unroll
                for (int r = 0; r < 4; r++)
                    xf[(mi * 16 + quad * 4 + r) * 264 + c] = xr[mi][nj][r];
        }
        __syncthreads();
        int row = t >> 3, pp = t & 7;
        const float* HW = (const float*)a.in[I_HW];
        float ah[12];
        #pragma unroll
        for (int c = 0; c < 12; c++) ah[c] = 0.0f;
        for (int kk = pp * 32; kk < pp * 32 + 32; kk++) {
            float xv = xf[row * 264 + kk];
            #pragma unroll
            for (int c = 0; c < 12; c++) ah[c] = fmaf(xv, HW[kk * 12 + c], ah[c]);
        }
        #pragma unroll
        for (int c = 0; c < 12; c++) {
            ah[c] += __shfl_xor(ah[c], 1);
            ah[c] += __shfl_xor(ah[c], 2);
            ah[c] += __shfl_xor(ah[c], 4);
        }
        if (pp == 0) {
            const float* hb = (const float*)a.in[I_HB];
            #pragma unroll
            for (int c = 0; c < 12; c++)
                a.out[(bid * MROWS + row) * AD + c] = ah[c] + hb[c];
        }
    }
}

extern "C" void kernel_launch(void* const* d_in, const int* in_sizes, int n_in,
                              void* d_out, int out_size, void* d_ws, size_t ws_size,
                              hipStream_t stream) {
    (void)in_sizes; (void)n_in; (void)out_size;
    Args a;
    for (int i = 0; i < N_IN; i++) a.in[i] = d_in[i];
    a.out = (float*)d_out;
    u16* ws16 = (u16*)d_ws;
    const bool use_ws = (ws_size >= (size_t)WS_BYTES) && (d_ws != nullptr);
    if (use_ws) {
        hipLaunchKernelGGL(prep_kernel, dim3(256, 20), dim3(256), 0, stream, a, ws16);
        hipFuncSetAttribute((const void*)yemong_mfma<true>, hipFuncAttributeMaxDynamicSharedMemorySize, SMEM_BYTES);
        hipLaunchKernelGGL((yemong_mfma<true>), dim3(NBLK), dim3(256), SMEM_BYTES, stream, a, ws16);
    } else {
        hipFuncSetAttribute((const void*)yemong_mfma<false>, hipFuncAttributeMaxDynamicSharedMemorySize, SMEM_BYTES);
        hipLaunchKernelGGL((yemong_mfma<false>), dim3(NBLK), dim3(256), SMEM_BYTES, stream, a, ws16);
    }
}

// Round 9
// 1124.096 us; speedup vs baseline: 1.1558x; 1.0087x over previous
//
#include <hip/hip_runtime.h>
#include <cstdint>

#define DEV __device__ __forceinline__

typedef __attribute__((ext_vector_type(8))) short short8;
typedef __attribute__((ext_vector_type(4))) float floatx4;
typedef unsigned short u16;
typedef unsigned int u32;

DEV u16 f2bf(float f) {
    unsigned u = __float_as_uint(f);
    return (u16)((u + 0x7fffu + ((u >> 16) & 1u)) >> 16);  // RNE
}
DEV void unpack2(u32 u, float& a, float& b) {
    a = __uint_as_float(u << 16);
    b = __uint_as_float(u & 0xffff0000u);
}
DEV u32 pack2f(float a, float b) { return (u32)f2bf(a) | ((u32)f2bf(b) << 16); }
DEV float sigm(float x) { return 1.0f / (1.0f + __expf(-x)); }

// Problem constants
#define NAG 8
#define DM 256
#define NL 4
#define AD 12
#define MROWS 32
#define NBLK 4096

// ws (bf16 units) offsets: weights in MFMA B-frag order [ks][n][quad][j]
#define OFF_E1   0
#define OFF_E2   8192
#define OFF_QKVO 73728        // 16 matrices of 65536: (l*4+m), m: 0=q 1=k 2=v 3=o
#define OFF_TW2  1122304
#define OFF_ADW  1126400
#define WS_TOTAL 1128448
#define WS_BYTES (WS_TOTAL * 2)

// dynamic LDS (bytes), total 68608 -> 2 blocks/CU (137 KB < 160 KB)
#define L_R1    0         // 33792: q[32][264]u16 @0 + k @16896 | trunk swizzled [256][64]u16 | head-x fp32
#define L_KB    16896
#define L_V     33792     // 16896: v[32][264]u16 (dedicated -> no mid-QKV barrier)
#define L_R2    50688     // 16896: state/nx [32][264]u16 ; bias tmp bf16 [4tok][4l][8h][64]
#define L_RED   67584     // 512: rms partials fp32 [32][4]
#define L_SPOS  68096     // 256
#define L_SVEL  68352     // 256
#define SMEM_BYTES 68608

// trunk swizzle: element (row, col) -> row*64 + ((col>>3 ^ (row&7))<<3) + (col&7)
#define TRK(row, col) ((row) * 64 + ((((col) >> 3) ^ ((row) & 7)) << 3) + ((col) & 7))

enum { I_STATE=0, I_POS, I_VEL, I_TEAM, I_ALIVE, I_DEAD, I_EW1, I_EB1, I_EW2, I_EB2,
       I_TEMB, I_SEMB, I_TW1, I_TB1, I_TW2, I_TB2, I_ADW, I_ADB, I_NORMW,
       I_WQ, I_BQ, I_WK, I_BK, I_WV, I_BV, I_WO, I_BO, I_HW, I_HB, N_IN };

struct Args { const void* in[N_IN]; float* out; };

// ---------------- weight pre-conversion: fp32 [K][N] -> bf16 frag order ----------------
__global__ __launch_bounds__(256) void prep_kernel(Args a, u16* ws)
{
    int e = blockIdx.x * 256 + threadIdx.x;
    int mat = blockIdx.y;
    int size, offs, N, Kreal;
    const float* src;
    if (mat == 0)      { size = 8192;  offs = OFF_E1;  N = 256; Kreal = 16;  src = (const float*)a.in[I_EW1]; }
    else if (mat == 1) { size = 65536; offs = OFF_E2;  N = 256; Kreal = 256; src = (const float*)a.in[I_EW2]; }
    else if (mat < 18) {
        int q = mat - 2, l = q >> 2, m = q & 3;
        int wi = (m == 0) ? I_WQ : (m == 1) ? I_WK : (m == 2) ? I_WV : I_WO;
        size = 65536; offs = OFF_QKVO + q * 65536; N = 256; Kreal = 256;
        src = (const float*)a.in[wi] + l * 65536;
    }
    else if (mat == 18) { size = 4096; offs = OFF_TW2; N = 64; Kreal = 64; src = (const float*)a.in[I_TW2]; }
    else                { size = 2048; offs = OFF_ADW; N = 32; Kreal = 64; src = (const float*)a.in[I_ADW]; }
    if (e >= size) return;
    int ksblk = N * 32;
    int ks = e / ksblk, rem = e % ksblk;
    int n = rem >> 5, quad = (rem >> 3) & 3, j = rem & 7;
    int k = ks * 32 + quad * 8 + j;
    float v = 0.0f;
    if (k < Kreal) {
        if (mat == 19) v = src[((n >> 3) * 64 + k) * 8 + (n & 7)];   // adapt_W[l][k][h], n=l*8+h
        else           v = src[k * N + n];
    }
    ws[offs + e] = f2bf(v);
}

// ---------------- MFMA fragment loaders (bit_cast, no unions) ----------------
DEV short8 ld_u4(const u16* p) {
    return __builtin_bit_cast(short8, *(const uint4*)p);
}
DEV short8 ld_afrag(const u16* A, int stride, int row0, int kofs, int l15, int quad) {
    return ld_u4(A + (row0 + l15) * stride + kofs + quad * 8);
}
DEV short8 ld_bws(const u16* w, int ksblk, int ks, int col, int l15, int quad) {
    return ld_u4(w + ks * ksblk + (col + l15) * 32 + quad * 8);
}
DEV short8 ld_bf32(const float* W, int N, int Kreal, int ks, int col, int l15, int quad) {
    short8 r;
    #pragma unroll
    for (int j = 0; j < 8; j++) {
        int k = ks * 32 + quad * 8 + j;
        float v = (k < Kreal) ? W[k * N + col + l15] : 0.0f;
        r[j] = (short)f2bf(v);
    }
    return r;
}

// M=32 GEMM: A [32][264] bf16 LDS, wave covers cols [colw, colw+64)
template<bool UW>
DEV void gemm32(const u16* A, const u16* wsW, const float* Wf,
                int Kb, int Kreal, int colw, int l15, int quad, floatx4 acc[2][4]) {
    for (int ks = 0; ks < Kb; ks++) {
        short8 af0 = ld_afrag(A, 264, 0,  ks * 32, l15, quad);
        short8 af1 = ld_afrag(A, 264, 16, ks * 32, l15, quad);
        short8 bf[4];
        #pragma unroll
        for (int nj = 0; nj < 4; nj++)
            bf[nj] = UW ? ld_bws(wsW, 8192, ks, colw + nj * 16, l15, quad)
                        : ld_bf32(Wf, 256, Kreal, ks, colw + nj * 16, l15, quad);
        #pragma unroll
        for (int nj = 0; nj < 4; nj++) {
            acc[0][nj] = __builtin_amdgcn_mfma_f32_16x16x32_bf16(af0, bf[nj], acc[0][nj], 0, 0, 0);
            acc[1][nj] = __builtin_amdgcn_mfma_f32_16x16x32_bf16(af1, bf[nj], acc[1][nj], 0, 0, 0);
        }
    }
}

template<bool UW>
__global__ __launch_bounds__(256, 2) void yemong_mfma(Args a, const u16* ws)
{
    extern __shared__ char smem[];
    u16* sR1   = (u16*)(smem + L_R1);     // q / trunk / head-x
    u16* skb   = (u16*)(smem + L_KB);     // k
    u16* sV    = (u16*)(smem + L_V);      // v
    u16* sR2   = (u16*)(smem + L_R2);     // state / nx / bias-tmp
    float* sred = (float*)(smem + L_RED);
    float* spos = (float*)(smem + L_SPOS);
    float* svel = (float*)(smem + L_SVEL);

    const int t = threadIdx.x, bid = blockIdx.x;
    const int lane = t & 63, w = t >> 6;
    const int l15 = lane & 15, quad = lane >> 4;
    const int colw = w * 64;
    const int p = w >> 1, h0 = (w & 1) * 4;   // attention pair / head base

    float xr[2][4][4];        // residual x (C-layout): row=mi*16+quad*4+r, col=colw+nj*16+l15
    u32 br[NL][4][2];         // attn bias, packed bf16 x4 per (layer, unit)
    u32 amask;                // alive bits of this lane's attention token

    // alive-layout probe (byte bools vs int32 bools), uniform
    unsigned mp = 0;
    const unsigned* au = (const unsigned*)a.in[I_ALIVE];
    #pragma unroll
    for (int i = 0; i < 16; i++) mp |= au[i];
    const bool abyte = (mp > 1u);
    auto aliveAt = [&](int r) -> int {
        int gi = bid * MROWS + r;
        return abyte ? (int)((const unsigned char*)a.in[I_ALIVE])[gi]
                     : ((const int*)a.in[I_ALIVE])[gi];
    };
    // rms partial: from xr, write sred (visibility via the next barrier)
    auto rms_partials = [&]() {
        float ssv[8];
        #pragma unroll
        for (int mi = 0; mi < 2; mi++)
            #pragma unroll
            for (int r = 0; r < 4; r++) {
                float s = 0.0f;
                #pragma unroll
                for (int nj = 0; nj < 4; nj++) { float v = xr[mi][nj][r]; s = fmaf(v, v, s); }
                ssv[mi * 4 + r] = s;
            }
        #pragma unroll
        for (int m = 1; m < 16; m <<= 1)
            #pragma unroll
            for (int k2 = 0; k2 < 8; k2++) ssv[k2] += __shfl_xor(ssv[k2], m);
        if (l15 == 0) {
            #pragma unroll
            for (int mi = 0; mi < 2; mi++)
                #pragma unroll
                for (int r = 0; r < 4; r++)
                    sred[(mi * 16 + quad * 4 + r) * 4 + w] = ssv[mi * 4 + r];
        }
    };

    // -------- P0: metadata + masked state staging --------
    if (t < 64) {
        int n = t >> 1, d = t & 1;
        spos[n * 2 + d] = ((const float*)a.in[I_POS])[(bid * MROWS + n) * 2 + d] * 1024.0f;
        svel[n * 2 + d] = ((const float*)a.in[I_VEL])[(bid * MROWS + n) * 2 + d];
    }
    {
        int tk = 2 * p + (quad >> 1);
        amask = 0;
        #pragma unroll
        for (int j = 0; j < 8; j++) amask |= (aliveAt(tk * 8 + j) ? 1u : 0u) << j;
    }
    {
        const float* gs = (const float*)a.in[I_STATE];
        const float* gd = (const float*)a.in[I_DEAD];
        #pragma unroll
        for (int it = 0; it < 4; it++) {
            int idx = t + 256 * it;              // 32 rows x 32 k
            int r = idx >> 5, kk = idx & 31;
            float v = 0.0f;
            if (kk < 16) v = aliveAt(r) ? gs[(bid * MROWS + r) * 16 + kk] : gd[kk];
            sR2[r * 264 + kk] = f2bf(v);
        }
    }
    __syncthreads();

    // -------- P1: enc1 (16->256) + silu, in place over R2 --------
    {
        floatx4 acc[2][4] = {};
        gemm32<UW>(sR2, ws + OFF_E1, (const float*)a.in[I_EW1], 1, 16, colw, l15, quad, acc);
        __syncthreads();
        const float* b1 = (const float*)a.in[I_EB1];
        #pragma unroll
        for (int nj = 0; nj < 4; nj++) {
            int c = colw + nj * 16 + l15;
            float bb = b1[c];
            #pragma unroll
            for (int mi = 0; mi < 2; mi++)
                #pragma unroll
                for (int r = 0; r < 4; r++) {
                    float v = acc[mi][nj][r] + bb;
                    sR2[(mi * 16 + quad * 4 + r) * 264 + c] = f2bf(v * sigm(v));
                }
        }
    }
    __syncthreads();

    // -------- P2: enc2 (256->256) + b2 + embeddings -> xr, then rms partials --------
    {
        floatx4 acc[2][4] = {};
        gemm32<UW>(sR2, ws + OFF_E2, (const float*)a.in[I_EW2], 8, 256, colw, l15, quad, acc);
        const float* b2 = (const float*)a.in[I_EB2];
        const float* te = (const float*)a.in[I_TEMB];
        const float* se = (const float*)a.in[I_SEMB];
        const int* gteam = (const int*)a.in[I_TEAM];
        int team8[8];
        #pragma unroll
        for (int mi = 0; mi < 2; mi++)
            #pragma unroll
            for (int r = 0; r < 4; r++)
                team8[mi * 4 + r] = gteam[bid * MROWS + mi * 16 + quad * 4 + r];
        #pragma unroll
        for (int nj = 0; nj < 4; nj++) {
            int c = colw + nj * 16 + l15;
            float bb = b2[c];
            #pragma unroll
            for (int mi = 0; mi < 2; mi++)
                #pragma unroll
                for (int r = 0; r < 4; r++) {
                    int row = mi * 16 + quad * 4 + r;
                    xr[mi][nj][r] = acc[mi][nj][r] + bb + te[team8[mi * 4 + r] * 256 + c] + se[(row & 7) * 256 + c];
                }
        }
        rms_partials();
    }

    // -------- P3a: pair features + trunk1 (6->64) + silu -> swizzled trunk [256][64] --------
    {
        int tokp = t >> 6;
        int pi = tokp * 8 + ((t >> 3) & 7), pj = tokp * 8 + (t & 7);
        float rx = spos[pi * 2 + 0] - spos[pj * 2 + 0];
        float ry = spos[pi * 2 + 1] - spos[pj * 2 + 1];
        rx -= rintf(rx * (1.0f / 1024.0f)) * 1024.0f;
        ry -= rintf(ry * (1.0f / 1024.0f)) * 1024.0f;
        float vx = svel[pi * 2 + 0] - svel[pj * 2 + 0];
        float vy = svel[pi * 2 + 1] - svel[pj * 2 + 1];
        float dn = sqrtf(rx * rx + ry * ry + 1e-8f) * (1.0f / 1024.0f);
        float f[6] = {rx * (1.0f / 1024.0f), ry * (1.0f / 1024.0f), vx, vy, dn, 1.0f / (1.0f + dn)};
        const float* W1 = (const float*)a.in[I_TW1];
        const float* B1 = (const float*)a.in[I_TB1];
        #pragma unroll
        for (int g = 0; g < 8; g++) {
            float v[8];
            #pragma unroll
            for (int e = 0; e < 8; e++) v[e] = B1[g * 8 + e];
            #pragma unroll
            for (int kk = 0; kk < 6; kk++)
                #pragma unroll
                for (int e = 0; e < 8; e++) v[e] = fmaf(f[kk], W1[kk * 64 + g * 8 + e], v[e]);
            #pragma unroll
            for (int e = 0; e < 8; e++) v[e] = v[e] * sigm(v[e]);
            uint4 pk;
            pk.x = pack2f(v[0], v[1]); pk.y = pack2f(v[2], v[3]);
            pk.z = pack2f(v[4], v[5]); pk.w = pack2f(v[6], v[7]);
            *(uint4*)&sR1[t * 64 + ((g ^ (t & 7)) << 3)] = pk;
        }
    }
    __syncthreads();

    // -------- P3b: trunk2 (64->64) MFMA, in place (wave-local rows, swizzled) --------
    {
        short8 taf[4][2];
        #pragma unroll
        for (int mi = 0; mi < 4; mi++)
            #pragma unroll
            for (int ks = 0; ks < 2; ks++) {
                int R = colw + mi * 16 + l15;
                taf[mi][ks] = ld_u4(&sR1[R * 64 + (((ks * 4 + quad) ^ (R & 7)) << 3)]);
            }
        floatx4 tacc[4][4] = {};
        #pragma unroll
        for (int ks = 0; ks < 2; ks++) {
            short8 bf[4];
            #pragma unroll
            for (int nj = 0; nj < 4; nj++)
                bf[nj] = UW ? ld_bws(ws + OFF_TW2, 2048, ks, nj * 16, l15, quad)
                            : ld_bf32((const float*)a.in[I_TW2], 64, 64, ks, nj * 16, l15, quad);
            #pragma unroll
            for (int mi = 0; mi < 4; mi++)
                #pragma unroll
                for (int nj = 0; nj < 4; nj++)
                    tacc[mi][nj] = __builtin_amdgcn_mfma_f32_16x16x32_bf16(taf[mi][ks], bf[nj], tacc[mi][nj], 0, 0, 0);
        }
        const float* B2 = (const float*)a.in[I_TB2];
        #pragma unroll
        for (int nj = 0; nj < 4; nj++) {
            int c = nj * 16 + l15;
            float bb = B2[c];
            #pragma unroll
            for (int mi = 0; mi < 4; mi++)
                #pragma unroll
                for (int r = 0; r < 4; r++) {
                    int row = colw + mi * 16 + quad * 4 + r;
                    sR1[TRK(row, c)] = f2bf(tacc[mi][nj][r] + bb);
                }
        }
    }
    __syncthreads();

    // -------- P3c: adapt (64->32) -> bias tmp (R2) -> bias regs --------
    {
        floatx4 tacc[4][2] = {};
        #pragma unroll
        for (int ks = 0; ks < 2; ks++) {
            short8 bf[2];
            #pragma unroll
            for (int nj = 0; nj < 2; nj++) {
                if (UW) bf[nj] = ld_bws(ws + OFF_ADW, 1024, ks, nj * 16, l15, quad);
                else {
                    const float* adw = (const float*)a.in[I_ADW];
                    int n = nj * 16 + l15;
                    #pragma unroll
                    for (int j = 0; j < 8; j++) {
                        int k = ks * 32 + quad * 8 + j;
                        bf[nj][j] = (short)f2bf(k < 64 ? adw[((n >> 3) * 64 + k) * 8 + (n & 7)] : 0.0f);
                    }
                }
            }
            #pragma unroll
            for (int mi = 0; mi < 4; mi++) {
                int R = colw + mi * 16 + l15;
                short8 af = ld_u4(&sR1[R * 64 + (((ks * 4 + quad) ^ (R & 7)) << 3)]);
                #pragma unroll
                for (int nj = 0; nj < 2; nj++)
                    tacc[mi][nj] = __builtin_amdgcn_mfma_f32_16x16x32_bf16(af, bf[nj], tacc[mi][nj], 0, 0, 0);
            }
        }
        const float* adb = (const float*)a.in[I_ADB];
        #pragma unroll
        for (int nj = 0; nj < 2; nj++) {
            int n = nj * 16 + l15;
            float bb = adb[n];
            #pragma unroll
            for (int mi = 0; mi < 4; mi++)
                #pragma unroll
                for (int r = 0; r < 4; r++) {
                    int pl = mi * 16 + quad * 4 + r;   // pair idx within token (wave = token)
                    sR2[((w * 4 + (n >> 3)) * 8 + (n & 7)) * 64 + pl] = f2bf(tacc[mi][nj][r] + bb);
                }
        }
        __syncthreads();
        // extract per-lane bias regs: for (layer, unit) 4 consecutive j values
        int tk = 2 * p + (quad >> 1);
        #pragma unroll
        for (int l = 0; l < NL; l++)
            #pragma unroll
            for (int u = 0; u < 4; u++) {
                int base = ((tk * 4 + l) * 8 + (h0 + u)) * 64 + (l15 & 7) * 8 + (quad & 1) * 4;
                const u32* bp = (const u32*)&sR2[base];
                br[l][u][0] = bp[0];
                br[l][u][1] = bp[1];
            }
    }
    __syncthreads();   // bias reads done; R2 free for nx

    // -------- P4: layers, 4 barriers each --------
    const float* normw = (const float*)a.in[I_NORMW];
    const bool qvalid = ((quad >> 1) == (l15 >> 3));
    #pragma unroll
    for (int l = 0; l < NL; l++) {
        // (a) rms finish (partials already in sred) + nx -> R2
        {
            float invr[8];
            #pragma unroll
            for (int mi = 0; mi < 2; mi++)
                #pragma unroll
                for (int r = 0; r < 4; r++) {
                    int row = mi * 16 + quad * 4 + r;
                    float s = sred[row * 4 + 0] + sred[row * 4 + 1] + sred[row * 4 + 2] + sred[row * 4 + 3];
                    invr[mi * 4 + r] = rsqrtf(s * (1.0f / 256.0f) + 1e-6f);
                }
            #pragma unroll
            for (int nj = 0; nj < 4; nj++) {
                int c = colw + nj * 16 + l15;
                float nwv = normw[l * 256 + c];
                #pragma unroll
                for (int mi = 0; mi < 2; mi++)
                    #pragma unroll
                    for (int r = 0; r < 4; r++)
                        sR2[(mi * 16 + quad * 4 + r) * 264 + c] = f2bf(xr[mi][nj][r] * invr[mi * 4 + r] * nwv);
            }
        }
        __syncthreads();   // [B1] nx visible

        // (b) fused Q/K/V projections; single store phase (V has own buffer)
        {
            floatx4 acc[3][2][4] = {};
            const u16* wq  = ws + OFF_QKVO + (l * 4 + 0) * 65536;
            const u16* wk  = ws + OFF_QKVO + (l * 4 + 1) * 65536;
            const u16* wvv = ws + OFF_QKVO + (l * 4 + 2) * 65536;
            const float* fq = (const float*)a.in[I_WQ] + l * 65536;
            const float* fk = (const float*)a.in[I_WK] + l * 65536;
            const float* fv = (const float*)a.in[I_WV] + l * 65536;
            #pragma unroll 2
            for (int ks = 0; ks < 8; ks++) {
                short8 af0 = ld_afrag(sR2, 264, 0,  ks * 32, l15, quad);
                short8 af1 = ld_afrag(sR2, 264, 16, ks * 32, l15, quad);
                short8 bq[4], bk[4], bv[4];
                #pragma unroll
                for (int nj = 0; nj < 4; nj++) {
                    int c = colw + nj * 16;
                    bq[nj] = UW ? ld_bws(wq,  8192, ks, c, l15, quad) : ld_bf32(fq, 256, 256, ks, c, l15, quad);
                    bk[nj] = UW ? ld_bws(wk,  8192, ks, c, l15, quad) : ld_bf32(fk, 256, 256, ks, c, l15, quad);
                    bv[nj] = UW ? ld_bws(wvv, 8192, ks, c, l15, quad) : ld_bf32(fv, 256, 256, ks, c, l15, quad);
                }
                #pragma unroll
                for (int nj = 0; nj < 4; nj++) {
                    acc[0][0][nj] = __builtin_amdgcn_mfma_f32_16x16x32_bf16(af0, bq[nj], acc[0][0][nj], 0, 0, 0);
                    acc[0][1][nj] = __builtin_amdgcn_mfma_f32_16x16x32_bf16(af1, bq[nj], acc[0][1][nj], 0, 0, 0);
                    acc[1][0][nj] = __builtin_amdgcn_mfma_f32_16x16x32_bf16(af0, bk[nj], acc[1][0][nj], 0, 0, 0);
                    acc[1][1][nj] = __builtin_amdgcn_mfma_f32_16x16x32_bf16(af1, bk[nj], acc[1][1][nj], 0, 0, 0);
                    acc[2][0][nj] = __builtin_amdgcn_mfma_f32_16x16x32_bf16(af0, bv[nj], acc[2][0][nj], 0, 0, 0);
                    acc[2][1][nj] = __builtin_amdgcn_mfma_f32_16x16x32_bf16(af1, bv[nj], acc[2][1][nj], 0, 0, 0);
                }
            }
            const float* bqf = (const float*)a.in[I_BQ] + l * 256;
            const float* bkf = (const float*)a.in[I_BK] + l * 256;
            const float* bvf = (const float*)a.in[I_BV] + l * 256;
            #pragma unroll
            for (int nj = 0; nj < 4; nj++) {
                int c = colw + nj * 16 + l15;
                float b0 = bqf[c], b1 = bkf[c], b2v = bvf[c];
                #pragma unroll
                for (int mi = 0; mi < 2; mi++)
                    #pragma unroll
                    for (int r = 0; r < 4; r++) {
                        int row = mi * 16 + quad * 4 + r;
                        sR1[row * 264 + c] = f2bf((acc[0][mi][nj][r] + b0) * 0.17677669529663689f);
                        skb[row * 264 + c] = f2bf(acc[1][mi][nj][r] + b1);
                        sV [row * 264 + c] = f2bf(acc[2][mi][nj][r] + b2v);
                    }
            }
        }
        __syncthreads();   // [B2] q, k, v visible

        // (c) MFMA attention: 4 units (pair p, head h0+u); batched score MFMAs
        {
            short8 kf[4], qf[4];
            #pragma unroll
            for (int u = 0; u < 4; u++) {
                int h = h0 + u;
                kf[u] = ld_u4(&skb[(p * 16 + l15) * 264 + h * 32 + quad * 8]);
                qf[u] = ld_u4(&sR1[(p * 16 + l15) * 264 + h * 32 + quad * 8]);
            }
            floatx4 st[4];
            #pragma unroll
            for (int u = 0; u < 4; u++) {
                floatx4 zero = {};
                st[u] = __builtin_amdgcn_mfma_f32_16x16x32_bf16(kf[u], qf[u], zero, 0, 0, 0);
            }
            short8 paf[4];
            #pragma unroll
            for (int u = 0; u < 4; u++) {
                float bb[4];
                unpack2(br[l][u][0], bb[0], bb[1]);
                unpack2(br[l][u][1], bb[2], bb[3]);
                float s[4];
                #pragma unroll
                for (int r = 0; r < 4; r++) {
                    int jl = (quad & 1) * 4 + r;
                    bool alv = (amask >> jl) & 1;
                    s[r] = qvalid ? (alv ? st[u][r] + bb[r] : -1.0e9f) : -2.0e9f;
                }
                float mx = fmaxf(fmaxf(s[0], s[1]), fmaxf(s[2], s[3]));
                mx = fmaxf(mx, __shfl_xor(mx, 16));
                mx = fmaxf(mx, __shfl_xor(mx, 32));
                float e[4], sm = 0.0f;
                #pragma unroll
                for (int r = 0; r < 4; r++) { e[r] = __expf(s[r] - mx); sm += e[r]; }
                sm += __shfl_xor(sm, 16);
                sm += __shfl_xor(sm, 32);
                float inv = 1.0f / sm;
                u32 u01 = pack2f(e[0] * inv, e[1] * inv);
                u32 u23 = pack2f(e[2] * inv, e[3] * inv);
                // redistribute P^T lanes into PV A-frag (k = quad*8 + jj)
                int srcA = (quad * 32 + l15) & 63;
                u32 a0 = (u32)__shfl((int)u01, srcA);
                u32 a1 = (u32)__shfl((int)u23, srcA);
                u32 a2 = (u32)__shfl((int)u01, (srcA + 16) & 63);
                u32 a3 = (u32)__shfl((int)u23, (srcA + 16) & 63);
                if (quad >= 2) { a0 = 0; a1 = 0; a2 = 0; a3 = 0; }
                uint4 tmp; tmp.x = a0; tmp.y = a1; tmp.z = a2; tmp.w = a3;
                paf[u] = __builtin_bit_cast(short8, tmp);
            }
            #pragma unroll
            for (int u = 0; u < 4; u++) {
                int h = h0 + u;
                #pragma unroll
                for (int nt = 0; nt < 2; nt++) {
                    short8 vf;
                    if (quad < 2) {
                        #pragma unroll
                        for (int jj = 0; jj < 8; jj++) {
                            int kr = quad * 8 + jj;
                            vf[jj] = (short)sV[(p * 16 + kr) * 264 + h * 32 + nt * 16 + l15];
                        }
                    } else {
                        #pragma unroll
                        for (int jj = 0; jj < 8; jj++) vf[jj] = 0;
                    }
                    floatx4 z2 = {};
                    floatx4 o = __builtin_amdgcn_mfma_f32_16x16x32_bf16(paf[u], vf, z2, 0, 0, 0);
                    #pragma unroll
                    for (int r = 0; r < 4; r++)
                        sR1[(p * 16 + quad * 4 + r) * 264 + h * 32 + nt * 16 + l15] = f2bf(o[r]);
                }
            }
        }
        __syncthreads();   // [B3] O visible

        // (d) x += O @ Wo + bo, then rms partials for next layer
        {
            floatx4 acc[2][4] = {};
            gemm32<UW>(sR1, ws + OFF_QKVO + (l * 4 + 3) * 65536, (const float*)a.in[I_WO] + l * 65536,
                       8, 256, colw, l15, quad, acc);
            const float* bo = (const float*)a.in[I_BO] + l * 256;
            #pragma unroll
            for (int nj = 0; nj < 4; nj++) {
                float bb = bo[colw + nj * 16 + l15];
                #pragma unroll
                for (int mi = 0; mi < 2; mi++)
                    #pragma unroll
                    for (int r = 0; r < 4; r++)
                        xr[mi][nj][r] += acc[mi][nj][r] + bb;
            }
            rms_partials();
        }
        __syncthreads();   // [B4] O reads + sred writes done
    }

    // -------- P5: stage x -> R1 fp32, then head (256 -> 12) --------
    {
        float* xf = (float*)sR1;
        #pragma unroll
        for (int nj = 0; nj < 4; nj++) {
            int c = colw + nj * 16 + l15;
            #pragma unroll
            for (int mi = 0; mi < 2; mi++)
                #pragma unroll
                for (int r = 0; r < 4; r++)
                    xf[(mi * 16 + quad * 4 + r) * 264 + c] = xr[mi][nj][r];
        }
        __syncthreads();
        int row = t >> 3, pp = t & 7;
        const float* HW = (const float*)a.in[I_HW];
        float ah[12];
        #pragma unroll
        for (int c = 0; c < 12; c++) ah[c] = 0.0f;
        for (int kk = pp * 32; kk < pp * 32 + 32; kk++) {
            float xv = xf[row * 264 + kk];
            #pragma unroll
            for (int c = 0; c < 12; c++) ah[c] = fmaf(xv, HW[kk * 12 + c], ah[c]);
        }
        #pragma unroll
        for (int c = 0; c < 12; c++) {
            ah[c] += __shfl_xor(ah[c], 1);
            ah[c] += __shfl_xor(ah[c], 2);
            ah[c] += __shfl_xor(ah[c], 4);
        }
        if (pp == 0) {
            const float* hb = (const float*)a.in[I_HB];
            #pragma unroll
            for (int c = 0; c < 12; c++)
                a.out[(bid * MROWS + row) * AD + c] = ah[c] + hb[c];
        }
    }
}

extern "C" void kernel_launch(void* const* d_in, const int* in_sizes, int n_in,
                              void* d_out, int out_size, void* d_ws, size_t ws_size,
                              hipStream_t stream) {
    (void)in_sizes; (void)n_in; (void)out_size;
    Args a;
    for (int i = 0; i < N_IN; i++) a.in[i] = d_in[i];
    a.out = (float*)d_out;
    u16* ws16 = (u16*)d_ws;
    const bool use_ws = (ws_size >= (size_t)WS_BYTES) && (d_ws != nullptr);
    if (use_ws) {
        hipLaunchKernelGGL(prep_kernel, dim3(256, 20), dim3(256), 0, stream, a, ws16);
        hipFuncSetAttribute((const void*)yemong_mfma<true>, hipFuncAttributeMaxDynamicSharedMemorySize, SMEM_BYTES);
        hipLaunchKernelGGL((yemong_mfma<true>), dim3(NBLK), dim3(256), SMEM_BYTES, stream, a, ws16);
    } else {
        hipFuncSetAttribute((const void*)yemong_mfma<false>, hipFuncAttributeMaxDynamicSharedMemorySize, SMEM_BYTES);
        hipLaunchKernelGGL((yemong_mfma<false>), dim3(NBLK), dim3(256), SMEM_BYTES, stream, a, ws16);
    }
}

// Round 10
// 981.548 us; speedup vs baseline: 1.3237x; 1.1452x over previous
//
#include <hip/hip_runtime.h>
#include <cstdint>

#define DEV __device__ __forceinline__

typedef __attribute__((ext_vector_type(8))) short short8;
typedef __attribute__((ext_vector_type(4))) float floatx4;
typedef unsigned short u16;
typedef unsigned int u32;

DEV u16 f2bf(float f) {
    unsigned u = __float_as_uint(f);
    return (u16)((u + 0x7fffu + ((u >> 16) & 1u)) >> 16);  // RNE
}
DEV void unpack2(u32 u, float& a, float& b) {
    a = __uint_as_float(u << 16);
    b = __uint_as_float(u & 0xffff0000u);
}
DEV u32 pack2f(float a, float b) { return (u32)f2bf(a) | ((u32)f2bf(b) << 16); }
DEV float sigm(float x) { return 1.0f / (1.0f + __expf(-x)); }

// Problem constants
#define NAG 8
#define DM 256
#define NL 4
#define AD 12
#define MROWS 64              // 8 tokens per block
#define NBLK 2048
#define THREADS 512

// ws (bf16 units) offsets: weights in MFMA B-frag order [ks][n][quad][j]
#define OFF_E1   0
#define OFF_E2   8192
#define OFF_QKVO 73728        // 16 matrices of 65536: (l*4+m), m: 0=q 1=k 2=v 3=o
#define OFF_TW2  1122304
#define OFF_ADW  1126400
#define WS_TOTAL 1128448
#define WS_BYTES (WS_TOTAL * 2)

// dynamic LDS (bytes), total 138240 -> 1 block/CU (8 waves)
#define L_R1    0         // 33792: q[64][264]u16 | trunk[0:33792] | head-x fp32 lo
#define L_KB    33792     // 33792: k[64][264]u16 | trunk[33792:] | head-x fp32 hi
#define L_V     67584     // 33792: v[64][264]u16
#define L_R2    101376    // 33792: state/nx [64][264]u16 ; bias tmp bf16 [8tok][4l][8h][64]
#define L_RED   135168    // 2048: rms partials fp32 [64][8]
#define L_SPOS  137216    // 512
#define L_SVEL  137728    // 512
#define SMEM_BYTES 138240

// trunk swizzle: element (row, col) -> row*64 + ((col>>3 ^ (row&7))<<3) + (col&7)
#define TRK(row, col) ((row) * 64 + ((((col) >> 3) ^ ((row) & 7)) << 3) + ((col) & 7))

enum { I_STATE=0, I_POS, I_VEL, I_TEAM, I_ALIVE, I_DEAD, I_EW1, I_EB1, I_EW2, I_EB2,
       I_TEMB, I_SEMB, I_TW1, I_TB1, I_TW2, I_TB2, I_ADW, I_ADB, I_NORMW,
       I_WQ, I_BQ, I_WK, I_BK, I_WV, I_BV, I_WO, I_BO, I_HW, I_HB, N_IN };

struct Args { const void* in[N_IN]; float* out; };

// ---------------- weight pre-conversion: fp32 [K][N] -> bf16 frag order ----------------
__global__ __launch_bounds__(256) void prep_kernel(Args a, u16* ws)
{
    int e = blockIdx.x * 256 + threadIdx.x;
    int mat = blockIdx.y;
    int size, offs, N, Kreal;
    const float* src;
    if (mat == 0)      { size = 8192;  offs = OFF_E1;  N = 256; Kreal = 16;  src = (const float*)a.in[I_EW1]; }
    else if (mat == 1) { size = 65536; offs = OFF_E2;  N = 256; Kreal = 256; src = (const float*)a.in[I_EW2]; }
    else if (mat < 18) {
        int q = mat - 2, l = q >> 2, m = q & 3;
        int wi = (m == 0) ? I_WQ : (m == 1) ? I_WK : (m == 2) ? I_WV : I_WO;
        size = 65536; offs = OFF_QKVO + q * 65536; N = 256; Kreal = 256;
        src = (const float*)a.in[wi] + l * 65536;
    }
    else if (mat == 18) { size = 4096; offs = OFF_TW2; N = 64; Kreal = 64; src = (const float*)a.in[I_TW2]; }
    else                { size = 2048; offs = OFF_ADW; N = 32; Kreal = 64; src = (const float*)a.in[I_ADW]; }
    if (e >= size) return;
    int ksblk = N * 32;
    int ks = e / ksblk, rem = e % ksblk;
    int n = rem >> 5, quad = (rem >> 3) & 3, j = rem & 7;
    int k = ks * 32 + quad * 8 + j;
    float v = 0.0f;
    if (k < Kreal) {
        if (mat == 19) v = src[((n >> 3) * 64 + k) * 8 + (n & 7)];   // adapt_W[l][k][h], n=l*8+h
        else           v = src[k * N + n];
    }
    ws[offs + e] = f2bf(v);
}

// ---------------- MFMA fragment loaders ----------------
DEV short8 ld_u4(const u16* p) {
    return __builtin_bit_cast(short8, *(const uint4*)p);
}
DEV short8 ld_afrag(const u16* A, int stride, int row0, int kofs, int l15, int quad) {
    return ld_u4(A + (row0 + l15) * stride + kofs + quad * 8);
}
DEV short8 ld_bws(const u16* w, int ksblk, int ks, int col, int l15, int quad) {
    return ld_u4(w + ks * ksblk + (col + l15) * 32 + quad * 8);
}
DEV short8 ld_bf32(const float* W, int N, int Kreal, int ks, int col, int l15, int quad) {
    short8 r;
    #pragma unroll
    for (int j = 0; j < 8; j++) {
        int k = ks * 32 + quad * 8 + j;
        float v = (k < Kreal) ? W[k * N + col + l15] : 0.0f;
        r[j] = (short)f2bf(v);
    }
    return r;
}

// M=64 GEMM: A [64][264] bf16 LDS, wave covers cols [colw, colw+32)
template<bool UW>
DEV void gemm64(const u16* A, const u16* wsW, const float* Wf,
                int Kb, int Kreal, int colw, int l15, int quad, floatx4 acc[4][2]) {
    #pragma unroll 2
    for (int ks = 0; ks < Kb; ks++) {
        short8 af[4];
        #pragma unroll
        for (int mi = 0; mi < 4; mi++)
            af[mi] = ld_afrag(A, 264, mi * 16, ks * 32, l15, quad);
        short8 bf[2];
        #pragma unroll
        for (int nj = 0; nj < 2; nj++)
            bf[nj] = UW ? ld_bws(wsW, 8192, ks, colw + nj * 16, l15, quad)
                        : ld_bf32(Wf, 256, Kreal, ks, colw + nj * 16, l15, quad);
        #pragma unroll
        for (int mi = 0; mi < 4; mi++)
            #pragma unroll
            for (int nj = 0; nj < 2; nj++)
                acc[mi][nj] = __builtin_amdgcn_mfma_f32_16x16x32_bf16(af[mi], bf[nj], acc[mi][nj], 0, 0, 0);
    }
}

template<bool UW>
__global__ __launch_bounds__(THREADS, 2) void yemong_mfma(Args a, const u16* ws)
{
    extern __shared__ char smem[];
    u16* sR1   = (u16*)(smem + L_R1);     // q / trunk-lo / head-x
    u16* skb   = (u16*)(smem + L_KB);     // k / trunk-hi
    u16* sV    = (u16*)(smem + L_V);      // v
    u16* sR2   = (u16*)(smem + L_R2);     // state / nx / bias-tmp
    float* sred = (float*)(smem + L_RED);
    float* spos = (float*)(smem + L_SPOS);
    float* svel = (float*)(smem + L_SVEL);

    const int t = threadIdx.x, bid = blockIdx.x;
    const int lane = t & 63, w = t >> 6;         // 8 waves
    const int l15 = lane & 15, quad = lane >> 4;
    const int colw = w * 32;                     // gemm col base (32 cols/wave)
    const int rowt = w * 64;                     // trunk row base
    const int p = w >> 1, h0 = (w & 1) * 4;      // attention pair / head base

    float xr[4][2][4];        // residual x (C-layout): row=mi*16+quad*4+r, col=colw+nj*16+l15
    u32 br[NL][4][2];         // attn bias, packed bf16 x4 per (layer, unit)
    u32 amask;                // alive bits of this lane's attention token

    // alive-layout probe (byte bools vs int32 bools), uniform
    unsigned mp = 0;
    const unsigned* au = (const unsigned*)a.in[I_ALIVE];
    #pragma unroll
    for (int i = 0; i < 16; i++) mp |= au[i];
    const bool abyte = (mp > 1u);
    auto aliveAt = [&](int r) -> int {
        int gi = bid * MROWS + r;
        return abyte ? (int)((const unsigned char*)a.in[I_ALIVE])[gi]
                     : ((const int*)a.in[I_ALIVE])[gi];
    };
    auto rms_partials = [&]() {
        float ssv[16];
        #pragma unroll
        for (int mi = 0; mi < 4; mi++)
            #pragma unroll
            for (int r = 0; r < 4; r++) {
                float x0 = xr[mi][0][r], x1 = xr[mi][1][r];
                ssv[mi * 4 + r] = fmaf(x0, x0, x1 * x1);
            }
        #pragma unroll
        for (int m = 1; m < 16; m <<= 1)
            #pragma unroll
            for (int k2 = 0; k2 < 16; k2++) ssv[k2] += __shfl_xor(ssv[k2], m);
        if (l15 == 0) {
            #pragma unroll
            for (int mi = 0; mi < 4; mi++)
                #pragma unroll
                for (int r = 0; r < 4; r++)
                    sred[(mi * 16 + quad * 4 + r) * 8 + w] = ssv[mi * 4 + r];
        }
    };

    // -------- P0: metadata + masked state staging --------
    if (t < 128) {
        int n = t >> 1, d = t & 1;
        spos[n * 2 + d] = ((const float*)a.in[I_POS])[(bid * MROWS + n) * 2 + d] * 1024.0f;
        svel[n * 2 + d] = ((const float*)a.in[I_VEL])[(bid * MROWS + n) * 2 + d];
    }
    {
        int tk = 2 * p + (quad >> 1);
        amask = 0;
        #pragma unroll
        for (int j = 0; j < 8; j++) amask |= (aliveAt(tk * 8 + j) ? 1u : 0u) << j;
    }
    {
        const float* gs = (const float*)a.in[I_STATE];
        const float* gd = (const float*)a.in[I_DEAD];
        #pragma unroll
        for (int it = 0; it < 4; it++) {
            int idx = t + THREADS * it;          // 64 rows x 32 k
            int r = idx >> 5, kk = idx & 31;
            float v = 0.0f;
            if (kk < 16) v = aliveAt(r) ? gs[(bid * MROWS + r) * 16 + kk] : gd[kk];
            sR2[r * 264 + kk] = f2bf(v);
        }
    }
    __syncthreads();

    // -------- P1: enc1 (16->256) + silu, in place over R2 --------
    {
        floatx4 acc[4][2] = {};
        gemm64<UW>(sR2, ws + OFF_E1, (const float*)a.in[I_EW1], 1, 16, colw, l15, quad, acc);
        __syncthreads();
        const float* b1 = (const float*)a.in[I_EB1];
        #pragma unroll
        for (int nj = 0; nj < 2; nj++) {
            int c = colw + nj * 16 + l15;
            float bb = b1[c];
            #pragma unroll
            for (int mi = 0; mi < 4; mi++)
                #pragma unroll
                for (int r = 0; r < 4; r++) {
                    float v = acc[mi][nj][r] + bb;
                    sR2[(mi * 16 + quad * 4 + r) * 264 + c] = f2bf(v * sigm(v));
                }
        }
    }
    __syncthreads();

    // -------- P2: enc2 (256->256) + b2 + embeddings -> xr, then rms partials --------
    {
        floatx4 acc[4][2] = {};
        gemm64<UW>(sR2, ws + OFF_E2, (const float*)a.in[I_EW2], 8, 256, colw, l15, quad, acc);
        const float* b2 = (const float*)a.in[I_EB2];
        const float* te = (const float*)a.in[I_TEMB];
        const float* se = (const float*)a.in[I_SEMB];
        const int* gteam = (const int*)a.in[I_TEAM];
        int team16[16];
        #pragma unroll
        for (int mi = 0; mi < 4; mi++)
            #pragma unroll
            for (int r = 0; r < 4; r++)
                team16[mi * 4 + r] = gteam[bid * MROWS + mi * 16 + quad * 4 + r];
        #pragma unroll
        for (int nj = 0; nj < 2; nj++) {
            int c = colw + nj * 16 + l15;
            float bb = b2[c];
            #pragma unroll
            for (int mi = 0; mi < 4; mi++)
                #pragma unroll
                for (int r = 0; r < 4; r++) {
                    int row = mi * 16 + quad * 4 + r;
                    xr[mi][nj][r] = acc[mi][nj][r] + bb + te[team16[mi * 4 + r] * 256 + c] + se[(row & 7) * 256 + c];
                }
        }
        rms_partials();
    }

    // -------- P3a: pair features + trunk1 (6->64) + silu -> swizzled trunk [512][64] --------
    {
        int tokp = t >> 6;
        int pi = tokp * 8 + ((t >> 3) & 7), pj = tokp * 8 + (t & 7);
        float rx = spos[pi * 2 + 0] - spos[pj * 2 + 0];
        float ry = spos[pi * 2 + 1] - spos[pj * 2 + 1];
        rx -= rintf(rx * (1.0f / 1024.0f)) * 1024.0f;
        ry -= rintf(ry * (1.0f / 1024.0f)) * 1024.0f;
        float vx = svel[pi * 2 + 0] - svel[pj * 2 + 0];
        float vy = svel[pi * 2 + 1] - svel[pj * 2 + 1];
        float dn = sqrtf(rx * rx + ry * ry + 1e-8f) * (1.0f / 1024.0f);
        float f[6] = {rx * (1.0f / 1024.0f), ry * (1.0f / 1024.0f), vx, vy, dn, 1.0f / (1.0f + dn)};
        const float* W1 = (const float*)a.in[I_TW1];
        const float* B1 = (const float*)a.in[I_TB1];
        #pragma unroll
        for (int g = 0; g < 8; g++) {
            float v[8];
            #pragma unroll
            for (int e = 0; e < 8; e++) v[e] = B1[g * 8 + e];
            #pragma unroll
            for (int kk = 0; kk < 6; kk++)
                #pragma unroll
                for (int e = 0; e < 8; e++) v[e] = fmaf(f[kk], W1[kk * 64 + g * 8 + e], v[e]);
            #pragma unroll
            for (int e = 0; e < 8; e++) v[e] = v[e] * sigm(v[e]);
            uint4 pk;
            pk.x = pack2f(v[0], v[1]); pk.y = pack2f(v[2], v[3]);
            pk.z = pack2f(v[4], v[5]); pk.w = pack2f(v[6], v[7]);
            *(uint4*)&sR1[t * 64 + ((g ^ (t & 7)) << 3)] = pk;
        }
    }
    __syncthreads();

    // -------- P3b: trunk2 (64->64) MFMA, in place (wave-local rows, swizzled) --------
    {
        short8 taf[4][2];
        #pragma unroll
        for (int mi = 0; mi < 4; mi++)
            #pragma unroll
            for (int ks = 0; ks < 2; ks++) {
                int R = rowt + mi * 16 + l15;
                taf[mi][ks] = ld_u4(&sR1[R * 64 + (((ks * 4 + quad) ^ (R & 7)) << 3)]);
            }
        floatx4 tacc[4][4] = {};
        #pragma unroll
        for (int ks = 0; ks < 2; ks++) {
            short8 bf[4];
            #pragma unroll
            for (int nj = 0; nj < 4; nj++)
                bf[nj] = UW ? ld_bws(ws + OFF_TW2, 2048, ks, nj * 16, l15, quad)
                            : ld_bf32((const float*)a.in[I_TW2], 64, 64, ks, nj * 16, l15, quad);
            #pragma unroll
            for (int mi = 0; mi < 4; mi++)
                #pragma unroll
                for (int nj = 0; nj < 4; nj++)
                    tacc[mi][nj] = __builtin_amdgcn_mfma_f32_16x16x32_bf16(taf[mi][ks], bf[nj], tacc[mi][nj], 0, 0, 0);
        }
        const float* B2 = (const float*)a.in[I_TB2];
        #pragma unroll
        for (int nj = 0; nj < 4; nj++) {
            int c = nj * 16 + l15;
            float bb = B2[c];
            #pragma unroll
            for (int mi = 0; mi < 4; mi++)
                #pragma unroll
                for (int r = 0; r < 4; r++) {
                    int row = rowt + mi * 16 + quad * 4 + r;
                    sR1[TRK(row, c)] = f2bf(tacc[mi][nj][r] + bb);
                }
        }
    }
    __syncthreads();

    // -------- P3c: adapt (64->32) -> bias tmp (R2) -> bias regs --------
    {
        floatx4 tacc[4][2] = {};
        #pragma unroll
        for (int ks = 0; ks < 2; ks++) {
            short8 bf[2];
            #pragma unroll
            for (int nj = 0; nj < 2; nj++) {
                if (UW) bf[nj] = ld_bws(ws + OFF_ADW, 1024, ks, nj * 16, l15, quad);
                else {
                    const float* adw = (const float*)a.in[I_ADW];
                    int n = nj * 16 + l15;
                    #pragma unroll
                    for (int j = 0; j < 8; j++) {
                        int k = ks * 32 + quad * 8 + j;
                        bf[nj][j] = (short)f2bf(k < 64 ? adw[((n >> 3) * 64 + k) * 8 + (n & 7)] : 0.0f);
                    }
                }
            }
            #pragma unroll
            for (int mi = 0; mi < 4; mi++) {
                int R = rowt + mi * 16 + l15;
                short8 af = ld_u4(&sR1[R * 64 + (((ks * 4 + quad) ^ (R & 7)) << 3)]);
                #pragma unroll
                for (int nj = 0; nj < 2; nj++)
                    tacc[mi][nj] = __builtin_amdgcn_mfma_f32_16x16x32_bf16(af, bf[nj], tacc[mi][nj], 0, 0, 0);
            }
        }
        const float* adb = (const float*)a.in[I_ADB];
        #pragma unroll
        for (int nj = 0; nj < 2; nj++) {
            int n = nj * 16 + l15;
            float bb = adb[n];
            #pragma unroll
            for (int mi = 0; mi < 4; mi++)
                #pragma unroll
                for (int r = 0; r < 4; r++) {
                    int pl = mi * 16 + quad * 4 + r;   // pair idx within token (wave = token w)
                    sR2[((w * 4 + (n >> 3)) * 8 + (n & 7)) * 64 + pl] = f2bf(tacc[mi][nj][r] + bb);
                }
        }
        __syncthreads();
        int tk = 2 * p + (quad >> 1);
        #pragma unroll
        for (int l = 0; l < NL; l++)
            #pragma unroll
            for (int u = 0; u < 4; u++) {
                int base = ((tk * 4 + l) * 8 + (h0 + u)) * 64 + (l15 & 7) * 8 + (quad & 1) * 4;
                const u32* bp = (const u32*)&sR2[base];
                br[l][u][0] = bp[0];
                br[l][u][1] = bp[1];
            }
    }
    __syncthreads();   // bias reads done; R2 free for nx

    // -------- P4: layers, 4 barriers each --------
    const float* normw = (const float*)a.in[I_NORMW];
    const bool qvalid = ((quad >> 1) == (l15 >> 3));
    #pragma unroll
    for (int l = 0; l < NL; l++) {
        // (a) rms finish + nx -> R2
        {
            float invr[16];
            #pragma unroll
            for (int mi = 0; mi < 4; mi++)
                #pragma unroll
                for (int r = 0; r < 4; r++) {
                    int row = mi * 16 + quad * 4 + r;
                    float4 pa = *(const float4*)&sred[row * 8];
                    float4 pb = *(const float4*)&sred[row * 8 + 4];
                    float s = pa.x + pa.y + pa.z + pa.w + pb.x + pb.y + pb.z + pb.w;
                    invr[mi * 4 + r] = rsqrtf(s * (1.0f / 256.0f) + 1e-6f);
                }
            #pragma unroll
            for (int nj = 0; nj < 2; nj++) {
                int c = colw + nj * 16 + l15;
                float nwv = normw[l * 256 + c];
                #pragma unroll
                for (int mi = 0; mi < 4; mi++)
                    #pragma unroll
                    for (int r = 0; r < 4; r++)
                        sR2[(mi * 16 + quad * 4 + r) * 264 + c] = f2bf(xr[mi][nj][r] * invr[mi * 4 + r] * nwv);
            }
        }
        __syncthreads();   // [B1] nx visible

        // (b) Q, K, V projections (separate buffers -> no internal barrier)
        {
            const float* bqf = (const float*)a.in[I_BQ] + l * 256;
            const float* bkf = (const float*)a.in[I_BK] + l * 256;
            const float* bvf = (const float*)a.in[I_BV] + l * 256;
            {
                floatx4 acc[4][2] = {};
                gemm64<UW>(sR2, ws + OFF_QKVO + (l * 4 + 0) * 65536, (const float*)a.in[I_WQ] + l * 65536, 8, 256, colw, l15, quad, acc);
                #pragma unroll
                for (int nj = 0; nj < 2; nj++) {
                    int c = colw + nj * 16 + l15;
                    float bb = bqf[c];
                    #pragma unroll
                    for (int mi = 0; mi < 4; mi++)
                        #pragma unroll
                        for (int r = 0; r < 4; r++)
                            sR1[(mi * 16 + quad * 4 + r) * 264 + c] = f2bf((acc[mi][nj][r] + bb) * 0.17677669529663689f);
                }
            }
            {
                floatx4 acc[4][2] = {};
                gemm64<UW>(sR2, ws + OFF_QKVO + (l * 4 + 1) * 65536, (const float*)a.in[I_WK] + l * 65536, 8, 256, colw, l15, quad, acc);
                #pragma unroll
                for (int nj = 0; nj < 2; nj++) {
                    int c = colw + nj * 16 + l15;
                    float bb = bkf[c];
                    #pragma unroll
                    for (int mi = 0; mi < 4; mi++)
                        #pragma unroll
                        for (int r = 0; r < 4; r++)
                            skb[(mi * 16 + quad * 4 + r) * 264 + c] = f2bf(acc[mi][nj][r] + bb);
                }
            }
            {
                floatx4 acc[4][2] = {};
                gemm64<UW>(sR2, ws + OFF_QKVO + (l * 4 + 2) * 65536, (const float*)a.in[I_WV] + l * 65536, 8, 256, colw, l15, quad, acc);
                #pragma unroll
                for (int nj = 0; nj < 2; nj++) {
                    int c = colw + nj * 16 + l15;
                    float bb = bvf[c];
                    #pragma unroll
                    for (int mi = 0; mi < 4; mi++)
                        #pragma unroll
                        for (int r = 0; r < 4; r++)
                            sV[(mi * 16 + quad * 4 + r) * 264 + c] = f2bf(acc[mi][nj][r] + bb);
                }
            }
        }
        __syncthreads();   // [B2] q, k, v visible

        // (c) MFMA attention: 4 units (pair p, head h0+u)
        {
            short8 kf[4], qf[4];
            #pragma unroll
            for (int u = 0; u < 4; u++) {
                int h = h0 + u;
                kf[u] = ld_u4(&skb[(p * 16 + l15) * 264 + h * 32 + quad * 8]);
                qf[u] = ld_u4(&sR1[(p * 16 + l15) * 264 + h * 32 + quad * 8]);
            }
            floatx4 st[4];
            #pragma unroll
            for (int u = 0; u < 4; u++) {
                floatx4 zero = {};
                st[u] = __builtin_amdgcn_mfma_f32_16x16x32_bf16(kf[u], qf[u], zero, 0, 0, 0);
            }
            short8 paf[4];
            #pragma unroll
            for (int u = 0; u < 4; u++) {
                float bb[4];
                unpack2(br[l][u][0], bb[0], bb[1]);
                unpack2(br[l][u][1], bb[2], bb[3]);
                float s[4];
                #pragma unroll
                for (int r = 0; r < 4; r++) {
                    int jl = (quad & 1) * 4 + r;
                    bool alv = (amask >> jl) & 1;
                    s[r] = qvalid ? (alv ? st[u][r] + bb[r] : -1.0e9f) : -2.0e9f;
                }
                float mx = fmaxf(fmaxf(s[0], s[1]), fmaxf(s[2], s[3]));
                mx = fmaxf(mx, __shfl_xor(mx, 16));
                mx = fmaxf(mx, __shfl_xor(mx, 32));
                float e[4], sm = 0.0f;
                #pragma unroll
                for (int r = 0; r < 4; r++) { e[r] = __expf(s[r] - mx); sm += e[r]; }
                sm += __shfl_xor(sm, 16);
                sm += __shfl_xor(sm, 32);
                float inv = 1.0f / sm;
                u32 u01 = pack2f(e[0] * inv, e[1] * inv);
                u32 u23 = pack2f(e[2] * inv, e[3] * inv);
                int srcA = (quad * 32 + l15) & 63;
                u32 a0 = (u32)__shfl((int)u01, srcA);
                u32 a1 = (u32)__shfl((int)u23, srcA);
                u32 a2 = (u32)__shfl((int)u01, (srcA + 16) & 63);
                u32 a3 = (u32)__shfl((int)u23, (srcA + 16) & 63);
                if (quad >= 2) { a0 = 0; a1 = 0; a2 = 0; a3 = 0; }
                uint4 tmp; tmp.x = a0; tmp.y = a1; tmp.z = a2; tmp.w = a3;
                paf[u] = __builtin_bit_cast(short8, tmp);
            }
            #pragma unroll
            for (int u = 0; u < 4; u++) {
                int h = h0 + u;
                #pragma unroll
                for (int nt = 0; nt < 2; nt++) {
                    short8 vf;
                    if (quad < 2) {
                        #pragma unroll
                        for (int jj = 0; jj < 8; jj++) {
                            int kr = quad * 8 + jj;
                            vf[jj] = (short)sV[(p * 16 + kr) * 264 + h * 32 + nt * 16 + l15];
                        }
                    } else {
                        #pragma unroll
                        for (int jj = 0; jj < 8; jj++) vf[jj] = 0;
                    }
                    floatx4 z2 = {};
                    floatx4 o = __builtin_amdgcn_mfma_f32_16x16x32_bf16(paf[u], vf, z2, 0, 0, 0);
                    #pragma unroll
                    for (int r = 0; r < 4; r++)
                        sR1[(p * 16 + quad * 4 + r) * 264 + h * 32 + nt * 16 + l15] = f2bf(o[r]);
                }
            }
        }
        __syncthreads();   // [B3] O visible

        // (d) x += O @ Wo + bo, then rms partials for next layer
        {
            floatx4 acc[4][2] = {};
            gemm64<UW>(sR1, ws + OFF_QKVO + (l * 4 + 3) * 65536, (const float*)a.in[I_WO] + l * 65536,
                       8, 256, colw, l15, quad, acc);
            const float* bo = (const float*)a.in[I_BO] + l * 256;
            #pragma unroll
            for (int nj = 0; nj < 2; nj++) {
                float bb = bo[colw + nj * 16 + l15];
                #pragma unroll
                for (int mi = 0; mi < 4; mi++)
                    #pragma unroll
                    for (int r = 0; r < 4; r++)
                        xr[mi][nj][r] += acc[mi][nj][r] + bb;
            }
            rms_partials();
        }
        __syncthreads();   // [B4] O reads + sred writes done
    }

    // -------- P5: stage x -> R1+KB fp32, then head (256 -> 12) --------
    {
        float* xf = (float*)sR1;     // [64][264] fp32 spans R1+KB
        #pragma unroll
        for (int nj = 0; nj < 2; nj++) {
            int c = colw + nj * 16 + l15;
            #pragma unroll
            for (int mi = 0; mi < 4; mi++)
                #pragma unroll
                for (int r = 0; r < 4; r++)
                    xf[(mi * 16 + quad * 4 + r) * 264 + c] = xr[mi][nj][r];
        }
        __syncthreads();
        int row = t >> 3, pp = t & 7;
        const float* HW = (const float*)a.in[I_HW];
        float ah[12];
        #pragma unroll
        for (int c = 0; c < 12; c++) ah[c] = 0.0f;
        for (int kk = pp * 32; kk < pp * 32 + 32; kk++) {
            float xv = xf[row * 264 + kk];
            #pragma unroll
            for (int c = 0; c < 12; c++) ah[c] = fmaf(xv, HW[kk * 12 + c], ah[c]);
        }
        #pragma unroll
        for (int c = 0; c < 12; c++) {
            ah[c] += __shfl_xor(ah[c], 1);
            ah[c] += __shfl_xor(ah[c], 2);
            ah[c] += __shfl_xor(ah[c], 4);
        }
        if (pp == 0) {
            const float* hb = (const float*)a.in[I_HB];
            #pragma unroll
            for (int c = 0; c < 12; c++)
                a.out[(bid * MROWS + row) * AD + c] = ah[c] + hb[c];
        }
    }
}

extern "C" void kernel_launch(void* const* d_in, const int* in_sizes, int n_in,
                              void* d_out, int out_size, void* d_ws, size_t ws_size,
                              hipStream_t stream) {
    (void)in_sizes; (void)n_in; (void)out_size;
    Args a;
    for (int i = 0; i < N_IN; i++) a.in[i] = d_in[i];
    a.out = (float*)d_out;
    u16* ws16 = (u16*)d_ws;
    const bool use_ws = (ws_size >= (size_t)WS_BYTES) && (d_ws != nullptr);
    if (use_ws) {
        hipLaunchKernelGGL(prep_kernel, dim3(256, 20), dim3(256), 0, stream, a, ws16);
        hipFuncSetAttribute((const void*)yemong_mfma<true>, hipFuncAttributeMaxDynamicSharedMemorySize, SMEM_BYTES);
        hipLaunchKernelGGL((yemong_mfma<true>), dim3(NBLK), dim3(THREADS), SMEM_BYTES, stream, a, ws16);
    } else {
        hipFuncSetAttribute((const void*)yemong_mfma<false>, hipFuncAttributeMaxDynamicSharedMemorySize, SMEM_BYTES);
        hipLaunchKernelGGL((yemong_mfma<false>), dim3(NBLK), dim3(THREADS), SMEM_BYTES, stream, a, ws16);
    }
}

// Round 12
// 964.051 us; speedup vs baseline: 1.3477x; 1.0181x over previous
//
#include <hip/hip_runtime.h>
#include <hip/hip_bf16.h>
#include <cstdint>

#define DEV __device__ __forceinline__

typedef __attribute__((ext_vector_type(8))) short short8;
typedef __attribute__((ext_vector_type(4))) float floatx4;
typedef unsigned short u16;
typedef unsigned int u32;

DEV u16 f2bf(float f) {
    unsigned u = __float_as_uint(f);
    return (u16)((u + 0x7fffu + ((u >> 16) & 1u)) >> 16);  // RNE
}
DEV void unpack2(u32 u, float& a, float& b) {
    a = __uint_as_float(u << 16);
    b = __uint_as_float(u & 0xffff0000u);
}
// HW packed f32x2 -> bf16x2 (v_cvt_pk_bf16_f32 on gfx95x), RNE
DEV u32 cvt2(float a, float b) {
    float2 f; f.x = a; f.y = b;
    __hip_bfloat162 h = __float22bfloat162_rn(f);
    u32 r;
    __builtin_memcpy(&r, &h, 4);
    return r;
}
DEV float sigm(float x) { return 1.0f / (1.0f + __expf(-x)); }

// Problem constants
#define NAG 8
#define DM 256
#define NL 4
#define AD 12
#define MROWS 64              // 8 tokens per block
#define NBLK 2048
#define THREADS 512

// ws (bf16 units) offsets: weights in MFMA B-frag order [ks][n][quad][j]
#define OFF_E1   0
#define OFF_E2   8192
#define OFF_QKVO 73728        // 16 matrices of 65536: (l*4+m), m: 0=q 1=k 2=v 3=o
#define OFF_TW2  1122304
#define OFF_ADW  1126400
#define WS_TOTAL 1128448
#define WS_BYTES (WS_TOTAL * 2)

// dynamic LDS (bytes), total 141440 -> 1 block/CU (8 waves)
#define L_R1    0         // 33792: q[64][264]u16 | trunk lo | head-x fp32 lo
#define L_KB    33792     // 33792: k[64][264]u16 | trunk hi | head-x fp32 hi
#define L_VT    67584     // 36992: V^T [256 cols][72 rows] u16
#define L_R2    104576    // 33792: state/nx [64][264]u16 ; bias tmp bf16 [8tok][4l][8h][64]
#define L_RED   138368    // 2048: rms partials fp32 [64][8]
#define L_SPOS  140416    // 512
#define L_SVEL  140928    // 512
#define SMEM_BYTES 141440

// trunk swizzle: element (row, col) -> row*64 + ((col>>3 ^ (row&7))<<3) + (col&7)
#define TRK(row, col) ((row) * 64 + ((((col) >> 3) ^ ((row) & 7)) << 3) + ((col) & 7))

enum { I_STATE=0, I_POS, I_VEL, I_TEAM, I_ALIVE, I_DEAD, I_EW1, I_EB1, I_EW2, I_EB2,
       I_TEMB, I_SEMB, I_TW1, I_TB1, I_TW2, I_TB2, I_ADW, I_ADB, I_NORMW,
       I_WQ, I_BQ, I_WK, I_BK, I_WV, I_BV, I_WO, I_BO, I_HW, I_HB, N_IN };

struct Args { const void* in[N_IN]; float* out; };

// ---------------- weight pre-conversion: fp32 [K][N] -> bf16 frag order ----------------
__global__ __launch_bounds__(256) void prep_kernel(Args a, u16* ws)
{
    int e = blockIdx.x * 256 + threadIdx.x;
    int mat = blockIdx.y;
    int size, offs, N, Kreal;
    const float* src;
    if (mat == 0)      { size = 8192;  offs = OFF_E1;  N = 256; Kreal = 16;  src = (const float*)a.in[I_EW1]; }
    else if (mat == 1) { size = 65536; offs = OFF_E2;  N = 256; Kreal = 256; src = (const float*)a.in[I_EW2]; }
    else if (mat < 18) {
        int q = mat - 2, l = q >> 2, m = q & 3;
        int wi = (m == 0) ? I_WQ : (m == 1) ? I_WK : (m == 2) ? I_WV : I_WO;
        size = 65536; offs = OFF_QKVO + q * 65536; N = 256; Kreal = 256;
        src = (const float*)a.in[wi] + l * 65536;
    }
    else if (mat == 18) { size = 4096; offs = OFF_TW2; N = 64; Kreal = 64; src = (const float*)a.in[I_TW2]; }
    else                { size = 2048; offs = OFF_ADW; N = 32; Kreal = 64; src = (const float*)a.in[I_ADW]; }
    if (e >= size) return;
    int ksblk = N * 32;
    int ks = e / ksblk, rem = e % ksblk;
    int n = rem >> 5, quad = (rem >> 3) & 3, j = rem & 7;
    int k = ks * 32 + quad * 8 + j;
    float v = 0.0f;
    if (k < Kreal) {
        if (mat == 19) v = src[((n >> 3) * 64 + k) * 8 + (n & 7)];   // adapt_W[l][k][h], n=l*8+h
        else           v = src[k * N + n];
    }
    ws[offs + e] = f2bf(v);
}

// ---------------- MFMA fragment loaders ----------------
DEV short8 ld_u4(const u16* p) {
    return __builtin_bit_cast(short8, *(const uint4*)p);
}
DEV short8 ld_afrag(const u16* A, int stride, int row0, int kofs, int l15, int quad) {
    return ld_u4(A + (row0 + l15) * stride + kofs + quad * 8);
}
DEV short8 ld_bws(const u16* w, int ksblk, int ks, int col, int l15, int quad) {
    return ld_u4(w + ks * ksblk + (col + l15) * 32 + quad * 8);
}
DEV short8 ld_bf32(const float* W, int N, int Kreal, int ks, int col, int l15, int quad) {
    short8 r;
    #pragma unroll
    for (int j = 0; j < 8; j++) {
        int k = ks * 32 + quad * 8 + j;
        float v = (k < Kreal) ? W[k * N + col + l15] : 0.0f;
        r[j] = (short)f2bf(v);
    }
    return r;
}

// M=64 GEMM: A [64][264] bf16 LDS, wave covers cols [colw, colw+32)
template<bool UW>
DEV void gemm64(const u16* A, const u16* wsW, const float* Wf,
                int Kb, int Kreal, int colw, int l15, int quad, floatx4 acc[4][2]) {
    #pragma unroll 4
    for (int ks = 0; ks < Kb; ks++) {
        short8 af[4];
        #pragma unroll
        for (int mi = 0; mi < 4; mi++)
            af[mi] = ld_afrag(A, 264, mi * 16, ks * 32, l15, quad);
        short8 bf[2];
        #pragma unroll
        for (int nj = 0; nj < 2; nj++)
            bf[nj] = UW ? ld_bws(wsW, 8192, ks, colw + nj * 16, l15, quad)
                        : ld_bf32(Wf, 256, Kreal, ks, colw + nj * 16, l15, quad);
        #pragma unroll
        for (int mi = 0; mi < 4; mi++)
            #pragma unroll
            for (int nj = 0; nj < 2; nj++)
                acc[mi][nj] = __builtin_amdgcn_mfma_f32_16x16x32_bf16(af[mi], bf[nj], acc[mi][nj], 0, 0, 0);
    }
}

template<bool UW>
__global__ __launch_bounds__(THREADS, 2) void yemong_mfma(Args a, const u16* ws)
{
    extern __shared__ char smem[];
    u16* sR1   = (u16*)(smem + L_R1);     // q / trunk-lo / head-x
    u16* skb   = (u16*)(smem + L_KB);     // k / trunk-hi
    u16* sVT   = (u16*)(smem + L_VT);     // V^T [col][row], stride 72
    u16* sR2   = (u16*)(smem + L_R2);     // state / nx / bias-tmp
    float* sred = (float*)(smem + L_RED);
    float* spos = (float*)(smem + L_SPOS);
    float* svel = (float*)(smem + L_SVEL);

    const int t = threadIdx.x, bid = blockIdx.x;
    const int lane = t & 63, w = t >> 6;         // 8 waves
    const int l15 = lane & 15, quad = lane >> 4;
    const int colw = w * 32;                     // gemm col base (32 cols/wave)
    const int rowt = w * 64;                     // trunk row base
    const int p = w >> 1, h0 = (w & 1) * 4;      // attention pair / head base

    float xr[4][2][4];        // residual x (C-layout): row=mi*16+quad*4+r, col=colw+nj*16+l15
    u32 br[NL][4][2];         // attn bias, packed bf16 x4 per (layer, unit)
    u32 amask;                // alive bits of this lane's attention token

    // alive-layout probe (byte bools vs int32 bools), uniform
    unsigned mp = 0;
    const unsigned* au = (const unsigned*)a.in[I_ALIVE];
    #pragma unroll
    for (int i = 0; i < 16; i++) mp |= au[i];
    const bool abyte = (mp > 1u);
    auto aliveAt = [&](int r) -> int {
        int gi = bid * MROWS + r;
        return abyte ? (int)((const unsigned char*)a.in[I_ALIVE])[gi]
                     : ((const int*)a.in[I_ALIVE])[gi];
    };
    auto rms_partials = [&]() {
        float ssv[16];
        #pragma unroll
        for (int mi = 0; mi < 4; mi++)
            #pragma unroll
            for (int r = 0; r < 4; r++) {
                float x0 = xr[mi][0][r], x1 = xr[mi][1][r];
                ssv[mi * 4 + r] = fmaf(x0, x0, x1 * x1);
            }
        #pragma unroll
        for (int m = 1; m < 16; m <<= 1)
            #pragma unroll
            for (int k2 = 0; k2 < 16; k2++) ssv[k2] += __shfl_xor(ssv[k2], m);
        if (l15 == 0) {
            #pragma unroll
            for (int mi = 0; mi < 4; mi++)
                #pragma unroll
                for (int r = 0; r < 4; r++)
                    sred[(mi * 16 + quad * 4 + r) * 8 + w] = ssv[mi * 4 + r];
        }
    };

    // -------- P0: metadata + masked state staging --------
    if (t < 128) {
        int n = t >> 1, d = t & 1;
        spos[n * 2 + d] = ((const float*)a.in[I_POS])[(bid * MROWS + n) * 2 + d] * 1024.0f;
        svel[n * 2 + d] = ((const float*)a.in[I_VEL])[(bid * MROWS + n) * 2 + d];
    }
    {
        int tk = 2 * p + (quad >> 1);
        amask = 0;
        #pragma unroll
        for (int j = 0; j < 8; j++) amask |= (aliveAt(tk * 8 + j) ? 1u : 0u) << j;
    }
    {
        const float* gs = (const float*)a.in[I_STATE];
        const float* gd = (const float*)a.in[I_DEAD];
        #pragma unroll
        for (int it = 0; it < 4; it++) {
            int idx = t + THREADS * it;          // 64 rows x 32 k
            int r = idx >> 5, kk = idx & 31;
            float v = 0.0f;
            if (kk < 16) v = aliveAt(r) ? gs[(bid * MROWS + r) * 16 + kk] : gd[kk];
            sR2[r * 264 + kk] = f2bf(v);
        }
    }
    __syncthreads();

    // -------- P1: enc1 (16->256) + silu, in place over R2 --------
    {
        floatx4 acc[4][2] = {};
        gemm64<UW>(sR2, ws + OFF_E1, (const float*)a.in[I_EW1], 1, 16, colw, l15, quad, acc);
        __syncthreads();
        const float* b1 = (const float*)a.in[I_EB1];
        #pragma unroll
        for (int nj = 0; nj < 2; nj++) {
            int c = colw + nj * 16 + l15;
            float bb = b1[c];
            #pragma unroll
            for (int mi = 0; mi < 4; mi++) {
                float v0 = acc[mi][nj][0] + bb, v1 = acc[mi][nj][1] + bb;
                float v2 = acc[mi][nj][2] + bb, v3 = acc[mi][nj][3] + bb;
                u32 lo = cvt2(v0 * sigm(v0), v1 * sigm(v1));
                u32 hi = cvt2(v2 * sigm(v2), v3 * sigm(v3));
                u16* b = &sR2[(mi * 16 + quad * 4) * 264 + c];
                b[0] = (u16)lo; b[264] = (u16)(lo >> 16);
                b[528] = (u16)hi; b[792] = (u16)(hi >> 16);
            }
        }
    }
    __syncthreads();

    // -------- P2: enc2 (256->256) + b2 + embeddings -> xr, then rms partials --------
    {
        floatx4 acc[4][2] = {};
        gemm64<UW>(sR2, ws + OFF_E2, (const float*)a.in[I_EW2], 8, 256, colw, l15, quad, acc);
        const float* b2 = (const float*)a.in[I_EB2];
        const float* te = (const float*)a.in[I_TEMB];
        const float* se = (const float*)a.in[I_SEMB];
        const int* gteam = (const int*)a.in[I_TEAM];
        int team16[16];
        #pragma unroll
        for (int mi = 0; mi < 4; mi++)
            #pragma unroll
            for (int r = 0; r < 4; r++)
                team16[mi * 4 + r] = gteam[bid * MROWS + mi * 16 + quad * 4 + r];
        #pragma unroll
        for (int nj = 0; nj < 2; nj++) {
            int c = colw + nj * 16 + l15;
            float bb = b2[c];
            #pragma unroll
            for (int mi = 0; mi < 4; mi++)
                #pragma unroll
                for (int r = 0; r < 4; r++) {
                    int row = mi * 16 + quad * 4 + r;
                    xr[mi][nj][r] = acc[mi][nj][r] + bb + te[team16[mi * 4 + r] * 256 + c] + se[(row & 7) * 256 + c];
                }
        }
        rms_partials();
    }

    // -------- P3a: pair features + trunk1 (6->64) + silu -> swizzled trunk [512][64] --------
    {
        int tokp = t >> 6;
        int pi = tokp * 8 + ((t >> 3) & 7), pj = tokp * 8 + (t & 7);
        float rx = spos[pi * 2 + 0] - spos[pj * 2 + 0];
        float ry = spos[pi * 2 + 1] - spos[pj * 2 + 1];
        rx -= rintf(rx * (1.0f / 1024.0f)) * 1024.0f;
        ry -= rintf(ry * (1.0f / 1024.0f)) * 1024.0f;
        float vx = svel[pi * 2 + 0] - svel[pj * 2 + 0];
        float vy = svel[pi * 2 + 1] - svel[pj * 2 + 1];
        float dn = sqrtf(rx * rx + ry * ry + 1e-8f) * (1.0f / 1024.0f);
        float f[6] = {rx * (1.0f / 1024.0f), ry * (1.0f / 1024.0f), vx, vy, dn, 1.0f / (1.0f + dn)};
        const float* W1 = (const float*)a.in[I_TW1];
        const float* B1 = (const float*)a.in[I_TB1];
        #pragma unroll
        for (int g = 0; g < 8; g++) {
            float v[8];
            #pragma unroll
            for (int e = 0; e < 8; e++) v[e] = B1[g * 8 + e];
            #pragma unroll
            for (int kk = 0; kk < 6; kk++)
                #pragma unroll
                for (int e = 0; e < 8; e++) v[e] = fmaf(f[kk], W1[kk * 64 + g * 8 + e], v[e]);
            #pragma unroll
            for (int e = 0; e < 8; e++) v[e] = v[e] * sigm(v[e]);
            uint4 pk;
            pk.x = cvt2(v[0], v[1]); pk.y = cvt2(v[2], v[3]);
            pk.z = cvt2(v[4], v[5]); pk.w = cvt2(v[6], v[7]);
            *(uint4*)&sR1[t * 64 + ((g ^ (t & 7)) << 3)] = pk;
        }
    }
    __syncthreads();

    // -------- P3b: trunk2 (64->64) MFMA, in place (wave-local rows, swizzled) --------
    {
        short8 taf[4][2];
        #pragma unroll
        for (int mi = 0; mi < 4; mi++)
            #pragma unroll
            for (int ks = 0; ks < 2; ks++) {
                int R = rowt + mi * 16 + l15;
                taf[mi][ks] = ld_u4(&sR1[R * 64 + (((ks * 4 + quad) ^ (R & 7)) << 3)]);
            }
        floatx4 tacc[4][4] = {};
        #pragma unroll
        for (int ks = 0; ks < 2; ks++) {
            short8 bf[4];
            #pragma unroll
            for (int nj = 0; nj < 4; nj++)
                bf[nj] = UW ? ld_bws(ws + OFF_TW2, 2048, ks, nj * 16, l15, quad)
                            : ld_bf32((const float*)a.in[I_TW2], 64, 64, ks, nj * 16, l15, quad);
            #pragma unroll
            for (int mi = 0; mi < 4; mi++)
                #pragma unroll
                for (int nj = 0; nj < 4; nj++)
                    tacc[mi][nj] = __builtin_amdgcn_mfma_f32_16x16x32_bf16(taf[mi][ks], bf[nj], tacc[mi][nj], 0, 0, 0);
        }
        const float* B2 = (const float*)a.in[I_TB2];
        #pragma unroll
        for (int nj = 0; nj < 4; nj++) {
            int c = nj * 16 + l15;
            float bb = B2[c];
            #pragma unroll
            for (int mi = 0; mi < 4; mi++)
                #pragma unroll
                for (int r = 0; r < 4; r++) {
                    int row = rowt + mi * 16 + quad * 4 + r;
                    sR1[TRK(row, c)] = f2bf(tacc[mi][nj][r] + bb);
                }
        }
    }
    __syncthreads();

    // -------- P3c: adapt (64->32) -> bias tmp (R2) -> bias regs --------
    {
        floatx4 tacc[4][2] = {};
        #pragma unroll
        for (int ks = 0; ks < 2; ks++) {
            short8 bf[2];
            #pragma unroll
            for (int nj = 0; nj < 2; nj++) {
                if (UW) bf[nj] = ld_bws(ws + OFF_ADW, 1024, ks, nj * 16, l15, quad);
                else {
                    const float* adw = (const float*)a.in[I_ADW];
                    int n = nj * 16 + l15;
                    #pragma unroll
                    for (int j = 0; j < 8; j++) {
                        int k = ks * 32 + quad * 8 + j;
                        bf[nj][j] = (short)f2bf(k < 64 ? adw[((n >> 3) * 64 + k) * 8 + (n & 7)] : 0.0f);
                    }
                }
            }
            #pragma unroll
            for (int mi = 0; mi < 4; mi++) {
                int R = rowt + mi * 16 + l15;
                short8 af = ld_u4(&sR1[R * 64 + (((ks * 4 + quad) ^ (R & 7)) << 3)]);
                #pragma unroll
                for (int nj = 0; nj < 2; nj++)
                    tacc[mi][nj] = __builtin_amdgcn_mfma_f32_16x16x32_bf16(af, bf[nj], tacc[mi][nj], 0, 0, 0);
            }
        }
        const float* adb = (const float*)a.in[I_ADB];
        #pragma unroll
        for (int nj = 0; nj < 2; nj++) {
            int n = nj * 16 + l15;
            float bb = adb[n];
            #pragma unroll
            for (int mi = 0; mi < 4; mi++)
                #pragma unroll
                for (int r = 0; r < 4; r++) {
                    int pl = mi * 16 + quad * 4 + r;   // pair idx within token (wave = token w)
                    sR2[((w * 4 + (n >> 3)) * 8 + (n & 7)) * 64 + pl] = f2bf(tacc[mi][nj][r] + bb);
                }
        }
        __syncthreads();
        int tk = 2 * p + (quad >> 1);
        #pragma unroll
        for (int l = 0; l < NL; l++)
            #pragma unroll
            for (int u = 0; u < 4; u++) {
                int base = ((tk * 4 + l) * 8 + (h0 + u)) * 64 + (l15 & 7) * 8 + (quad & 1) * 4;
                const u32* bp = (const u32*)&sR2[base];
                br[l][u][0] = bp[0];
                br[l][u][1] = bp[1];
            }
    }
    __syncthreads();   // bias reads done; R2 free for nx

    // -------- P4: layers, 4 barriers each --------
    const float* normw = (const float*)a.in[I_NORMW];
    const bool qvalid = ((quad >> 1) == (l15 >> 3));
    #pragma unroll
    for (int l = 0; l < NL; l++) {
        // (a) rms finish + nx -> R2
        {
            float invr[16];
            #pragma unroll
            for (int mi = 0; mi < 4; mi++)
                #pragma unroll
                for (int r = 0; r < 4; r++) {
                    int row = mi * 16 + quad * 4 + r;
                    float4 pa = *(const float4*)&sred[row * 8];
                    float4 pb = *(const float4*)&sred[row * 8 + 4];
                    float s = pa.x + pa.y + pa.z + pa.w + pb.x + pb.y + pb.z + pb.w;
                    invr[mi * 4 + r] = rsqrtf(s * (1.0f / 256.0f) + 1e-6f);
                }
            #pragma unroll
            for (int nj = 0; nj < 2; nj++) {
                int c = colw + nj * 16 + l15;
                float nwv = normw[l * 256 + c];
                #pragma unroll
                for (int mi = 0; mi < 4; mi++) {
                    u32 lo = cvt2(xr[mi][nj][0] * invr[mi * 4 + 0] * nwv, xr[mi][nj][1] * invr[mi * 4 + 1] * nwv);
                    u32 hi = cvt2(xr[mi][nj][2] * invr[mi * 4 + 2] * nwv, xr[mi][nj][3] * invr[mi * 4 + 3] * nwv);
                    u16* b = &sR2[(mi * 16 + quad * 4) * 264 + c];
                    b[0] = (u16)lo; b[264] = (u16)(lo >> 16);
                    b[528] = (u16)hi; b[792] = (u16)(hi >> 16);
                }
            }
        }
        __syncthreads();   // [B1] nx visible

        // (b) Q, K, V projections (separate buffers -> no internal barrier)
        {
            const float* bqf = (const float*)a.in[I_BQ] + l * 256;
            const float* bkf = (const float*)a.in[I_BK] + l * 256;
            const float* bvf = (const float*)a.in[I_BV] + l * 256;
            {
                floatx4 acc[4][2] = {};
                gemm64<UW>(sR2, ws + OFF_QKVO + (l * 4 + 0) * 65536, (const float*)a.in[I_WQ] + l * 65536, 8, 256, colw, l15, quad, acc);
                #pragma unroll
                for (int nj = 0; nj < 2; nj++) {
                    int c = colw + nj * 16 + l15;
                    float bb = bqf[c];
                    #pragma unroll
                    for (int mi = 0; mi < 4; mi++) {
                        u32 lo = cvt2((acc[mi][nj][0] + bb) * 0.17677669529663689f, (acc[mi][nj][1] + bb) * 0.17677669529663689f);
                        u32 hi = cvt2((acc[mi][nj][2] + bb) * 0.17677669529663689f, (acc[mi][nj][3] + bb) * 0.17677669529663689f);
                        u16* b = &sR1[(mi * 16 + quad * 4) * 264 + c];
                        b[0] = (u16)lo; b[264] = (u16)(lo >> 16);
                        b[528] = (u16)hi; b[792] = (u16)(hi >> 16);
                    }
                }
            }
            {
                floatx4 acc[4][2] = {};
                gemm64<UW>(sR2, ws + OFF_QKVO + (l * 4 + 1) * 65536, (const float*)a.in[I_WK] + l * 65536, 8, 256, colw, l15, quad, acc);
                #pragma unroll
                for (int nj = 0; nj < 2; nj++) {
                    int c = colw + nj * 16 + l15;
                    float bb = bkf[c];
                    #pragma unroll
                    for (int mi = 0; mi < 4; mi++) {
                        u32 lo = cvt2(acc[mi][nj][0] + bb, acc[mi][nj][1] + bb);
                        u32 hi = cvt2(acc[mi][nj][2] + bb, acc[mi][nj][3] + bb);
                        u16* b = &skb[(mi * 16 + quad * 4) * 264 + c];
                        b[0] = (u16)lo; b[264] = (u16)(lo >> 16);
                        b[528] = (u16)hi; b[792] = (u16)(hi >> 16);
                    }
                }
            }
            {
                floatx4 acc[4][2] = {};
                gemm64<UW>(sR2, ws + OFF_QKVO + (l * 4 + 2) * 65536, (const float*)a.in[I_WV] + l * 65536, 8, 256, colw, l15, quad, acc);
                #pragma unroll
                for (int nj = 0; nj < 2; nj++) {
                    int c = colw + nj * 16 + l15;
                    float bb = bvf[c];
                    #pragma unroll
                    for (int mi = 0; mi < 4; mi++) {
                        uint2 pk;
                        pk.x = cvt2(acc[mi][nj][0] + bb, acc[mi][nj][1] + bb);
                        pk.y = cvt2(acc[mi][nj][2] + bb, acc[mi][nj][3] + bb);
                        *(uint2*)&sVT[c * 72 + mi * 16 + quad * 4] = pk;   // V^T, b64 store
                    }
                }
            }
        }
        __syncthreads();   // [B2] q, k, v visible

        // (c) MFMA attention: 4 units (pair p, head h0+u)
        {
            short8 kf[4], qf[4];
            #pragma unroll
            for (int u = 0; u < 4; u++) {
                int h = h0 + u;
                kf[u] = ld_u4(&skb[(p * 16 + l15) * 264 + h * 32 + quad * 8]);
                qf[u] = ld_u4(&sR1[(p * 16 + l15) * 264 + h * 32 + quad * 8]);
            }
            floatx4 st[4];
            #pragma unroll
            for (int u = 0; u < 4; u++) {
                floatx4 zero = {};
                st[u] = __builtin_amdgcn_mfma_f32_16x16x32_bf16(kf[u], qf[u], zero, 0, 0, 0);
            }
            short8 paf[4];
            #pragma unroll
            for (int u = 0; u < 4; u++) {
                float bb[4];
                unpack2(br[l][u][0], bb[0], bb[1]);
                unpack2(br[l][u][1], bb[2], bb[3]);
                float s[4];
                #pragma unroll
                for (int r = 0; r < 4; r++) {
                    int jl = (quad & 1) * 4 + r;
                    bool alv = (amask >> jl) & 1;
                    s[r] = qvalid ? (alv ? st[u][r] + bb[r] : -1.0e9f) : -2.0e9f;
                }
                float mx = fmaxf(fmaxf(s[0], s[1]), fmaxf(s[2], s[3]));
                mx = fmaxf(mx, __shfl_xor(mx, 16));
                mx = fmaxf(mx, __shfl_xor(mx, 32));
                float e[4], sm = 0.0f;
                #pragma unroll
                for (int r = 0; r < 4; r++) { e[r] = __expf(s[r] - mx); sm += e[r]; }
                sm += __shfl_xor(sm, 16);
                sm += __shfl_xor(sm, 32);
                float inv = 1.0f / sm;
                u32 u01 = cvt2(e[0] * inv, e[1] * inv);
                u32 u23 = cvt2(e[2] * inv, e[3] * inv);
                int srcA = (quad * 32 + l15) & 63;
                u32 a0 = (u32)__shfl((int)u01, srcA);
                u32 a1 = (u32)__shfl((int)u23, srcA);
                u32 a2 = (u32)__shfl((int)u01, (srcA + 16) & 63);
                u32 a3 = (u32)__shfl((int)u23, (srcA + 16) & 63);
                if (quad >= 2) { a0 = 0; a1 = 0; a2 = 0; a3 = 0; }
                uint4 tmp; tmp.x = a0; tmp.y = a1; tmp.z = a2; tmp.w = a3;
                paf[u] = __builtin_bit_cast(short8, tmp);
            }
            #pragma unroll
            for (int u = 0; u < 4; u++) {
                int h = h0 + u;
                #pragma unroll
                for (int nt = 0; nt < 2; nt++) {
                    short8 vf;
                    if (quad < 2) {
                        vf = ld_u4(&sVT[(h * 32 + nt * 16 + l15) * 72 + p * 16 + quad * 8]);  // one b128
                    } else {
                        uint4 z = {};
                        vf = __builtin_bit_cast(short8, z);
                    }
                    floatx4 z2 = {};
                    floatx4 o = __builtin_amdgcn_mfma_f32_16x16x32_bf16(paf[u], vf, z2, 0, 0, 0);
                    u32 lo = cvt2(o[0], o[1]);
                    u32 hi = cvt2(o[2], o[3]);
                    u16* ob = &sR1[(p * 16 + quad * 4) * 264 + h * 32 + nt * 16 + l15];
                    ob[0] = (u16)lo; ob[264] = (u16)(lo >> 16);
                    ob[528] = (u16)hi; ob[792] = (u16)(hi >> 16);
                }
            }
        }
        __syncthreads();   // [B3] O visible

        // (d) x += O @ Wo + bo, then rms partials for next layer
        {
            floatx4 acc[4][2] = {};
            gemm64<UW>(sR1, ws + OFF_QKVO + (l * 4 + 3) * 65536, (const float*)a.in[I_WO] + l * 65536,
                       8, 256, colw, l15, quad, acc);
            const float* bo = (const float*)a.in[I_BO] + l * 256;
            #pragma unroll
            for (int nj = 0; nj < 2; nj++) {
                float bb = bo[colw + nj * 16 + l15];
                #pragma unroll
                for (int mi = 0; mi < 4; mi++)
                    #pragma unroll
                    for (int r = 0; r < 4; r++)
                        xr[mi][nj][r] += acc[mi][nj][r] + bb;
            }
            rms_partials();
        }
        __syncthreads();   // [B4] O reads + sred writes done
    }

    // -------- P5: stage x -> R1+KB fp32, then head (256 -> 12) --------
    {
        float* xf = (float*)sR1;     // [64][264] fp32 spans R1+KB
        #pragma unroll
        for (int nj = 0; nj < 2; nj++) {
            int c = colw + nj * 16 + l15;
            #pragma unroll
            for (int mi = 0; mi < 4; mi++)
                #pragma unroll
                for (int r = 0; r < 4; r++)
                    xf[(mi * 16 + quad * 4 + r) * 264 + c] = xr[mi][nj][r];
        }
        __syncthreads();
        int row = t >> 3, pp = t & 7;
        const float* HW = (const float*)a.in[I_HW];
        float ah[12];
        #pragma unroll
        for (int c = 0; c < 12; c++) ah[c] = 0.0f;
        for (int kk = pp * 32; kk < pp * 32 + 32; kk++) {
            float xv = xf[row * 264 + kk];
            #pragma unroll
            for (int c = 0; c < 12; c++) ah[c] = fmaf(xv, HW[kk * 12 + c], ah[c]);
        }
        #pragma unroll
        for (int c = 0; c < 12; c++) {
            ah[c] += __shfl_xor(ah[c], 1);
            ah[c] += __shfl_xor(ah[c], 2);
            ah[c] += __shfl_xor(ah[c], 4);
        }
        if (pp == 0) {
            const float* hb = (const float*)a.in[I_HB];
            #pragma unroll
            for (int c = 0; c < 12; c++)
                a.out[(bid * MROWS + row) * AD + c] = ah[c] + hb[c];
        }
    }
}

extern "C" void kernel_launch(void* const* d_in, const int* in_sizes, int n_in,
                              void* d_out, int out_size, void* d_ws, size_t ws_size,
                              hipStream_t stream) {
    (void)in_sizes; (void)n_in; (void)out_size;
    Args a;
    for (int i = 0; i < N_IN; i++) a.in[i] = d_in[i];
    a.out = (float*)d_out;
    u16* ws16 = (u16*)d_ws;
    const bool use_ws = (ws_size >= (size_t)WS_BYTES) && (d_ws != nullptr);
    if (use_ws) {
        hipLaunchKernelGGL(prep_kernel, dim3(256, 20), dim3(256), 0, stream, a, ws16);
        (void)hipFuncSetAttribute((const void*)yemong_mfma<true>, hipFuncAttributeMaxDynamicSharedMemorySize, SMEM_BYTES);
        hipLaunchKernelGGL((yemong_mfma<true>), dim3(NBLK), dim3(THREADS), SMEM_BYTES, stream, a, ws16);
    } else {
        (void)hipFuncSetAttribute((const void*)yemong_mfma<false>, hipFuncAttributeMaxDynamicSharedMemorySize, SMEM_BYTES);
        hipLaunchKernelGGL((yemong_mfma<false>), dim3(NBLK), dim3(THREADS), SMEM_BYTES, stream, a, ws16);
    }
}